// Round 3
// baseline (2764.873 us; speedup 1.0000x reference)
//
#include <hip/hip_runtime.h>
#include <math.h>
#include <stdint.h>

#define N_TOK 16384
#define DIM   1024
#define NEXP  8
#define HID   2048
#define OUTD  1024
#define PADTOT 33792   // 2*N_TOK + 8*128 : padded compacted-row upper bound (264 tiles)

typedef __attribute__((ext_vector_type(8))) short short8;
typedef __attribute__((ext_vector_type(8))) _Float16 f16x8;
typedef __attribute__((ext_vector_type(4))) float f32x4;
typedef __attribute__((ext_vector_type(4))) unsigned short u16x4;

__device__ __forceinline__ unsigned short f2h(float f) {
  return __builtin_bit_cast(unsigned short, (_Float16)f);   // RNE
}
__device__ __forceinline__ float gelu_exact(float a) {
  return 0.5f * a * (1.0f + erff(a * 0.70710678118654752f));
}

// ---------------- gate: fp64 for routing robustness, no LDS ----------------
__global__ __launch_bounds__(256) void gate_kernel(
    const float* __restrict__ x, const float* __restrict__ Wg1,
    const float* __restrict__ Wg2,
    int* __restrict__ tok_e, float* __restrict__ tok_w, int* __restrict__ cnt)
{
  const int tid = threadIdx.x;
  const int lane = tid & 63, wid = tid >> 6;
  const int wave_global = blockIdx.x * 4 + wid;     // 0..1023
  const f32x4* __restrict__ Wg1v = (const f32x4*)Wg1;   // [1024][4]
  for (int t = 0; t < N_TOK / 1024; ++t) {
    const int n = wave_global * (N_TOK / 1024) + t;
    double acc[16];
#pragma unroll
    for (int j = 0; j < 16; ++j) acc[j] = 0.0;
    for (int it = 0; it < DIM / 64; ++it) {
      int d = it * 64 + lane;
      double xv = (double)x[(size_t)n * DIM + d];
      f32x4 w0 = Wg1v[(size_t)d * 4 + 0];
      f32x4 w1 = Wg1v[(size_t)d * 4 + 1];
      f32x4 w2 = Wg1v[(size_t)d * 4 + 2];
      f32x4 w3 = Wg1v[(size_t)d * 4 + 3];
#pragma unroll
      for (int q = 0; q < 4; ++q) {
        acc[q]      += xv * (double)w0[q];
        acc[4 + q]  += xv * (double)w1[q];
        acc[8 + q]  += xv * (double)w2[q];
        acc[12 + q] += xv * (double)w3[q];
      }
    }
#pragma unroll
    for (int j = 0; j < 16; ++j) {
#pragma unroll
      for (int s = 32; s > 0; s >>= 1) acc[j] += __shfl_xor(acc[j], s);
    }
    // select acc[lane&15] without dynamic indexing (rule #20)
    const int jl = lane & 15;
    double av = acc[0];
#pragma unroll
    for (int j = 1; j < 16; ++j) av = (jl == j) ? acc[j] : av;
    double tmine = tanh(av);
    const int e = lane & 7;
    double ge = 0.0;
#pragma unroll
    for (int j = 0; j < 16; ++j) {
      double tj = __shfl(tmine, j);
      ge += tj * (double)Wg2[j * 8 + e];
    }
    double m = ge;
#pragma unroll
    for (int s = 1; s < 8; s <<= 1) m = fmax(m, __shfl_xor(m, s));
    double p = exp(ge - m);
    double ssum = p;
#pragma unroll
    for (int s = 1; s < 8; s <<= 1) ssum += __shfl_xor(ssum, s);
    double wsm = p / ssum;
    unsigned long long key =
        (((unsigned long long)__double_as_longlong(wsm)) & ~7ULL) |
        (unsigned long long)(7 - e);
    unsigned long long k1 = key;
#pragma unroll
    for (int s = 1; s < 8; s <<= 1) { unsigned long long o = __shfl_xor(k1, s); k1 = (o > k1) ? o : k1; }
    int e1 = 7 - (int)(k1 & 7ULL);
    unsigned long long k2 = (e == e1) ? 0ULL : key;
#pragma unroll
    for (int s = 1; s < 8; s <<= 1) { unsigned long long o = __shfl_xor(k2, s); k2 = (o > k2) ? o : k2; }
    int e2 = 7 - (int)(k2 & 7ULL);
    double w1v = __longlong_as_double((long long)(k1 & ~7ULL));
    double w2v = __longlong_as_double((long long)(k2 & ~7ULL));
    double inv = 1.0 / (w1v + w2v + 1e-12);
    if (lane == 0) {
      tok_e[2 * n] = e1; tok_e[2 * n + 1] = e2;
      tok_w[2 * n] = (float)(w1v * inv); tok_w[2 * n + 1] = (float)(w2v * inv);
      atomicAdd(&cnt[e1], 1); atomicAdd(&cnt[e2], 1);
    }
  }
}

// offsets padded to multiples of 128 so every 128-row tile is single-expert
__global__ void offsets_kernel(const int* __restrict__ cnt, int* __restrict__ off,
                               int* __restrict__ cur) {
  if (threadIdx.x == 0) {
    int a = 0;
    for (int e = 0; e < NEXP; ++e) {
      off[e] = a; cur[e] = a;
      a += (cnt[e] + 127) & ~127;
    }
    off[NEXP] = a;
  }
}

__global__ __launch_bounds__(256) void scatter_kernel(
    const int* __restrict__ tok_e, const float* __restrict__ tok_w,
    int* __restrict__ cur, int* __restrict__ rows, float* __restrict__ roww,
    int* __restrict__ pair)
{
  int n = blockIdx.x * 256 + threadIdx.x;
  if (n >= N_TOK) return;
#pragma unroll
  for (int k = 0; k < 2; ++k) {
    int e = tok_e[2 * n + k];
    int pos = atomicAdd(&cur[e], 1);
    rows[pos] = n;
    roww[pos] = tok_w[2 * n + k];
    pair[2 * n + k] = pos;
  }
}

// ---------------- fp32 -> fp16 converts ----------------
__global__ __launch_bounds__(256) void convert_x_kernel(
    const float* __restrict__ x, unsigned short* __restrict__ xh)
{
  size_t i = ((size_t)blockIdx.x * 256 + threadIdx.x) * 8;
  f32x4 a = *(const f32x4*)(x + i);
  f32x4 b = *(const f32x4*)(x + i + 4);
  short8 o;
#pragma unroll
  for (int q = 0; q < 4; ++q) { o[q] = (short)f2h(a[q]); o[q + 4] = (short)f2h(b[q]); }
  *(short8*)(xh + i) = o;
}

// transpose+convert: W[e][K][N] fp32 -> Wt[e][N][K] fp16
__global__ __launch_bounds__(256) void wconv_kernel(
    const float* __restrict__ W, unsigned short* __restrict__ Wt,
    const int K, const int N)
{
  __shared__ float t[32][33];
  const int e = blockIdx.z;
  const float* We = W + (size_t)e * K * N;
  unsigned short* Wte = Wt + (size_t)e * K * N;
  const int n0 = blockIdx.x * 32, k0 = blockIdx.y * 32;
  const int tid = threadIdx.x;
  const int r = tid >> 3, c4 = (tid & 7) * 4;
  f32x4 v = *(const f32x4*)(We + (size_t)(k0 + r) * N + n0 + c4);
  t[r][c4 + 0] = v[0]; t[r][c4 + 1] = v[1]; t[r][c4 + 2] = v[2]; t[r][c4 + 3] = v[3];
  __syncthreads();
  u16x4 o;
#pragma unroll
  for (int q = 0; q < 4; ++q) o[q] = f2h(t[c4 + q][r]);
  *(u16x4*)(Wte + (size_t)(n0 + r) * K + k0 + c4) = o;
}

// ---------------- routed GEMM (fp16 MFMA, fp32 acc, dbuf prefetch) ----------------
// MODE 0: A = gathered xh rows (via rows[]), out = act1f chunk-local (acc+bias)
// MODE 1: A = act2 chunk-local,              out = act1f chunk-local (acc+bias)
// MODE 2: A = act2 chunk-local,              out = d_out atomicAdd(w*(acc+bias))  [fallback]
// MODE 3: A = act2 chunk-local,              out = Y rows w*(acc+bias)            [combine later]
template<int MODE>
__global__ __launch_bounds__(256) void gemm_kernel(
    const unsigned short* __restrict__ Abase,
    const unsigned short* __restrict__ Bbase,
    float* __restrict__ Obase,
    const float* __restrict__ bias,
    const int* __restrict__ rows,
    const float* __restrict__ roww,
    const int* __restrict__ off,
    const int K, const int N, const int Astride, const int c0, const int lgGX)
{
  // XCD-chunked bijective block remap (m204): consecutive work ids share an XCD's L2
  const unsigned orig = blockIdx.x, nwg = gridDim.x;
  const unsigned q8 = nwg >> 3, r8 = nwg & 7;
  const unsigned xcd = orig & 7, pos = orig >> 3;
  const unsigned wrk = (xcd < r8 ? xcd * (q8 + 1) : r8 * (q8 + 1) + (xcd - r8) * q8) + pos;
  const int tn = (int)(wrk & ((1u << lgGX) - 1u));
  const int rowbase = c0 + (int)(wrk >> lgGX) * 128;

  const int off8 = off[NEXP];
  if (rowbase >= off8) return;
  int e = 0;
  while (e < NEXP - 1 && rowbase >= off[e + 1]) ++e;

  __shared__ __align__(16) unsigned short ldsA[2][128 * 64];
  __shared__ __align__(16) unsigned short ldsB[2][128 * 64];

  const int tid = threadIdx.x, lane = tid & 63, wid = tid >> 6;
  const int wm = wid >> 1, wn = wid & 1;
  const int l15 = lane & 15, lh = lane >> 4;

  f32x4 acc[4][4] = {};

  // staging: chunk c = i*256+tid -> LDS bytes c*16 (linear, lane-contiguous per wave)
  // slot (row, s) holds logical k-chunk s^(row&7): pre-swizzled GLOBAL source (T2 both-sides)
  size_t aoff[4], boff[4];
#pragma unroll
  for (int i = 0; i < 4; ++i) {
    int c = i * 256 + tid;
    int row = c >> 3;
    int kc = ((c & 7) ^ (row & 7)) * 8;
    size_t arow;
    if (MODE == 0) arow = (size_t)rows[rowbase + row];
    else           arow = (size_t)(rowbase - c0 + row);
    aoff[i] = arow * (size_t)Astride + kc;
    boff[i] = ((size_t)e * N + (size_t)(tn * 128 + row)) * K + kc;
  }

  auto stage = [&](int b, int k0) {
#pragma unroll
    for (int i = 0; i < 4; ++i) {
      int c = i * 256 + tid;
      __builtin_amdgcn_global_load_lds(
          (const __attribute__((address_space(1))) void*)(Abase + aoff[i] + k0),
          (__attribute__((address_space(3))) void*)(&ldsA[b][c * 8]), 16, 0, 0);
      __builtin_amdgcn_global_load_lds(
          (const __attribute__((address_space(1))) void*)(Bbase + boff[i] + k0),
          (__attribute__((address_space(3))) void*)(&ldsB[b][c * 8]), 16, 0, 0);
    }
  };

  const int nk = K >> 6;
  stage(0, 0);
  __syncthreads();                 // implicit vmcnt(0) drain + barrier
  int buf = 0;
  for (int t = 0; t < nk; ++t) {
    if (t + 1 < nk) stage(buf ^ 1, (t + 1) * 64);   // prefetch overlaps compute below
#pragma unroll
    for (int kk = 0; kk < 2; ++kk) {
      short8 af[4], bf[4];
#pragma unroll
      for (int mi = 0; mi < 4; ++mi) {
        int row = wm * 64 + mi * 16 + l15;
        int chunk = (kk * 4 + lh) ^ (row & 7);
        af[mi] = *(const short8*)(&ldsA[buf][row * 64 + chunk * 8]);
      }
#pragma unroll
      for (int ni = 0; ni < 4; ++ni) {
        int row = wn * 64 + ni * 16 + l15;
        int chunk = (kk * 4 + lh) ^ (row & 7);
        bf[ni] = *(const short8*)(&ldsB[buf][row * 64 + chunk * 8]);
      }
#pragma unroll
      for (int mi = 0; mi < 4; ++mi)
#pragma unroll
        for (int ni = 0; ni < 4; ++ni)
          acc[mi][ni] = __builtin_amdgcn_mfma_f32_16x16x32_f16(
              __builtin_bit_cast(f16x8, bf[ni]),
              __builtin_bit_cast(f16x8, af[mi]),
              acc[mi][ni], 0, 0, 0);   // D[n][token]: lane holds token=l15, n=lh*4+q
    }
    __syncthreads();                // drains this wave's prefetch (vmcnt 0) + sync
    buf ^= 1;
  }

#pragma unroll
  for (int mi = 0; mi < 4; ++mi) {
    int rowloc = wm * 64 + mi * 16 + l15;
    int g = rowbase + rowloc;
    if (MODE == 2) {
      int token = rows[g];
      float wgt = roww[g];
#pragma unroll
      for (int ni = 0; ni < 4; ++ni) {
        int n = tn * 128 + wn * 64 + ni * 16 + lh * 4;
        f32x4 v = acc[mi][ni];
        f32x4 bv = *(const f32x4*)(bias + (size_t)e * N + n);
#pragma unroll
        for (int qd = 0; qd < 4; ++qd)
          atomicAdd(&Obase[(size_t)token * N + n + qd], wgt * (v[qd] + bv[qd]));
      }
    } else if (MODE == 3) {
      float wgt = roww[g];
#pragma unroll
      for (int ni = 0; ni < 4; ++ni) {
        int n = tn * 128 + wn * 64 + ni * 16 + lh * 4;
        f32x4 v = acc[mi][ni];
        f32x4 bv = *(const f32x4*)(bias + (size_t)e * N + n);
        f32x4 o;
#pragma unroll
        for (int qd = 0; qd < 4; ++qd) o[qd] = wgt * (v[qd] + bv[qd]);
        *(f32x4*)(Obase + (size_t)g * N + n) = o;
      }
    } else {
      size_t orow = (size_t)(g - c0) * N;
#pragma unroll
      for (int ni = 0; ni < 4; ++ni) {
        int n = tn * 128 + wn * 64 + ni * 16 + lh * 4;
        f32x4 v = acc[mi][ni];
        f32x4 bv = *(const f32x4*)(bias + (size_t)e * N + n);
        f32x4 o;
#pragma unroll
        for (int qd = 0; qd < 4; ++qd) o[qd] = v[qd] + bv[qd];
        *(f32x4*)(Obase + orow + n) = o;
      }
    }
  }
}

// ---------------- LayerNorm + exact GELU: fp32 in, fp16 out ----------------
__global__ __launch_bounds__(256) void ln_gelu_kernel(
    const float* __restrict__ src, unsigned short* __restrict__ dst,
    const float* __restrict__ gam, const float* __restrict__ bet,
    const int* __restrict__ off, const int c0)
{
  const int g = c0 + blockIdx.x;
  if (g >= off[NEXP]) return;
  int e = 0;
  while (e < NEXP - 1 && g >= off[e + 1]) ++e;
  const int tid = threadIdx.x;
  const float* s0 = src + (size_t)(g - c0) * HID;
  f32x4 a = *(const f32x4*)(s0 + tid * 8);
  f32x4 b = *(const f32x4*)(s0 + tid * 8 + 4);
  float s = 0.f, sq = 0.f;
#pragma unroll
  for (int q = 0; q < 4; ++q) { s += a[q] + b[q]; sq += a[q] * a[q] + b[q] * b[q]; }
#pragma unroll
  for (int sh = 32; sh > 0; sh >>= 1) { s += __shfl_xor(s, sh); sq += __shfl_xor(sq, sh); }
  __shared__ float rs_[4], rq_[4];
  const int lane = tid & 63, wid = tid >> 6;
  if (lane == 0) { rs_[wid] = s; rq_[wid] = sq; }
  __syncthreads();
  s  = rs_[0] + rs_[1] + rs_[2] + rs_[3];
  sq = rq_[0] + rq_[1] + rq_[2] + rq_[3];
  const float mu  = s * (1.0f / HID);
  const float var = sq * (1.0f / HID) - mu * mu;
  const float rstd = rsqrtf(var + 1e-5f);
  const float* gp = gam + (size_t)e * HID + tid * 8;
  const float* bp = bet + (size_t)e * HID + tid * 8;
  short8 o;
#pragma unroll
  for (int q = 0; q < 8; ++q) {
    float v = (q < 4) ? a[q] : b[q - 4];
    float t = (v - mu) * rstd * gp[q] + bp[q];
    o[q] = (short)f2h(gelu_exact(t));
  }
  *(short8*)(dst + (size_t)(g - c0) * HID + tid * 8) = o;
}

// ---------------- deterministic 2-row combine ----------------
__global__ __launch_bounds__(256) void combine_kernel(
    const float* __restrict__ Y, const int* __restrict__ pair,
    float* __restrict__ out)
{
  const int n = blockIdx.x;
  const int j = threadIdx.x * 4;
  const int r1 = pair[2 * n], r2 = pair[2 * n + 1];
  f32x4 v1 = *(const f32x4*)(Y + (size_t)r1 * OUTD + j);
  f32x4 v2 = *(const f32x4*)(Y + (size_t)r2 * OUTD + j);
  f32x4 o;
#pragma unroll
  for (int qd = 0; qd < 4; ++qd) o[qd] = v1[qd] + v2[qd];
  *(f32x4*)(out + (size_t)n * OUTD + j) = o;
}

// fallback diagnostic: encode ws_size (MB) into out[0]
__global__ void probe_kernel(float* out, float v) {
  if (threadIdx.x == 0 && blockIdx.x == 0) out[0] = v;
}

extern "C" void kernel_launch(void* const* d_in, const int* in_sizes, int n_in,
                              void* d_out, int out_size, void* d_ws, size_t ws_size,
                              hipStream_t stream) {
  (void)in_sizes; (void)n_in;
  const float* x   = (const float*)d_in[0];
  const float* Wg1 = (const float*)d_in[1];
  const float* Wg2 = (const float*)d_in[2];
  const float* W1  = (const float*)d_in[3];
  const float* b1  = (const float*)d_in[4];
  const float* g1  = (const float*)d_in[5];
  const float* be1 = (const float*)d_in[6];
  const float* W2  = (const float*)d_in[7];
  const float* b2  = (const float*)d_in[8];
  const float* g2  = (const float*)d_in[9];
  const float* be2 = (const float*)d_in[10];
  const float* W3  = (const float*)d_in[11];
  const float* b3  = (const float*)d_in[12];
  float* out = (float*)d_out;

  uint8_t* w = (uint8_t*)d_ws;
  auto alloc = [&](size_t bytes) {
    uint8_t* p = w;
    w += (bytes + 255) & ~(size_t)255;
    return p;
  };
  unsigned short* xh   = (unsigned short*)alloc((size_t)N_TOK * DIM * 2);
  unsigned short* Wt1  = (unsigned short*)alloc((size_t)NEXP * DIM * HID * 2);
  unsigned short* Wt2  = (unsigned short*)alloc((size_t)NEXP * HID * HID * 2);
  unsigned short* Wt3  = (unsigned short*)alloc((size_t)NEXP * HID * OUTD * 2);
  int*   rows  = (int*)alloc((size_t)PADTOT * 4);
  float* roww  = (float*)alloc((size_t)PADTOT * 4);
  int*   tok_e = (int*)alloc((size_t)2 * N_TOK * 4);
  float* tok_w = (float*)alloc((size_t)2 * N_TOK * 4);
  int*   pair  = (int*)alloc((size_t)2 * N_TOK * 4);
  int*   cnt   = (int*)alloc(256);
  int*   off   = (int*)alloc(256);
  int*   cur   = (int*)alloc(256);
  size_t fixed_used = (size_t)(w - (uint8_t*)d_ws);

  // adaptive chunk rows: act1f (fp32, R*HID) + act2 (fp16, R*HID) = 12288 B/row
  long long availLL = (long long)ws_size - (long long)fixed_used - 4096;
  int R = 0;
  if (availLL > 0) {
    long long r = availLL / (HID * 4 + HID * 2);
    if (r > PADTOT) r = PADTOT;
    R = (int)(r & ~127LL);
  }
  if (R < 128) {   // diagnostic fallback: out[0] = ws_size in MB
    hipMemsetAsync(d_out, 0, (size_t)out_size * sizeof(float), stream);
    probe_kernel<<<1, 64, 0, stream>>>(out, (float)(ws_size >> 20));
    return;
  }
  float*          act1f = (float*)alloc((size_t)R * HID * 4);
  unsigned short* act2  = (unsigned short*)alloc((size_t)R * HID * 2);
  const bool single = (R >= PADTOT);   // Y (fp32 [PADTOT][1024]) aliases act1f
  float* Yf = act1f;

  hipMemsetAsync(cnt, 0, NEXP * sizeof(int), stream);
  hipMemsetAsync(rows, 0, (size_t)PADTOT * 4, stream);   // dummy rows -> token 0
  hipMemsetAsync(roww, 0, (size_t)PADTOT * 4, stream);   // dummy weight -> 0.0
  if (!single)
    hipMemsetAsync(d_out, 0, (size_t)out_size * sizeof(float), stream);  // atomic target

  gate_kernel<<<256, 256, 0, stream>>>(x, Wg1, Wg2, tok_e, tok_w, cnt);
  offsets_kernel<<<1, 64, 0, stream>>>(cnt, off, cur);
  scatter_kernel<<<N_TOK / 256, 256, 0, stream>>>(tok_e, tok_w, cur, rows, roww, pair);

  convert_x_kernel<<<(N_TOK * DIM / 8) / 256, 256, 0, stream>>>(x, xh);
  wconv_kernel<<<dim3(HID / 32, DIM / 32, NEXP), 256, 0, stream>>>(W1, Wt1, DIM, HID);
  wconv_kernel<<<dim3(HID / 32, HID / 32, NEXP), 256, 0, stream>>>(W2, Wt2, HID, HID);
  wconv_kernel<<<dim3(OUTD / 32, HID / 32, NEXP), 256, 0, stream>>>(W3, Wt3, HID, OUTD);

  for (int c0 = 0; c0 < PADTOT; c0 += R) {
    int Rc = PADTOT - c0; if (Rc > R) Rc = R;
    const int yt = Rc / 128;
    gemm_kernel<0><<<16 * yt, 256, 0, stream>>>(xh, Wt1, act1f, b1, rows, roww, off,
                                                DIM, HID, DIM, c0, 4);
    ln_gelu_kernel<<<Rc, 256, 0, stream>>>(act1f, act2, g1, be1, off, c0);
    gemm_kernel<1><<<16 * yt, 256, 0, stream>>>(act2, Wt2, act1f, b2, rows, roww, off,
                                                HID, HID, HID, c0, 4);
    ln_gelu_kernel<<<Rc, 256, 0, stream>>>(act1f, act2, g2, be2, off, c0);
    if (single)
      gemm_kernel<3><<<8 * yt, 256, 0, stream>>>(act2, Wt3, Yf, b3, rows, roww, off,
                                                 HID, OUTD, HID, c0, 3);
    else
      gemm_kernel<2><<<8 * yt, 256, 0, stream>>>(act2, Wt3, out, b3, rows, roww, off,
                                                 HID, OUTD, HID, c0, 3);
  }
  if (single)
    combine_kernel<<<N_TOK, 256, 0, stream>>>(Yf, pair, out);
}

// Round 4
// 2074.292 us; speedup vs baseline: 1.3329x; 1.3329x over previous
//
#include <hip/hip_runtime.h>
#include <math.h>
#include <stdint.h>

#define N_TOK 16384
#define DIM   1024
#define NEXP  8
#define HID   2048
#define OUTD  1024
#define PADTOT 33792   // 2*N_TOK + 8*128 : padded compacted-row upper bound (264 tiles)

typedef __attribute__((ext_vector_type(8))) short short8;
typedef __attribute__((ext_vector_type(8))) _Float16 f16x8;
typedef __attribute__((ext_vector_type(4))) float f32x4;
typedef __attribute__((ext_vector_type(4))) unsigned short u16x4;

__device__ __forceinline__ unsigned short f2h(float f) {
  return __builtin_bit_cast(unsigned short, (_Float16)f);   // RNE
}
__device__ __forceinline__ float h2f(unsigned short h) {
  return (float)__builtin_bit_cast(_Float16, h);
}
__device__ __forceinline__ float gelu_exact(float a) {
  return 0.5f * a * (1.0f + erff(a * 0.70710678118654752f));
}

// ---------------- gate: fp64 for routing robustness, no LDS ----------------
__global__ __launch_bounds__(256) void gate_kernel(
    const float* __restrict__ x, const float* __restrict__ Wg1,
    const float* __restrict__ Wg2,
    int* __restrict__ tok_e, float* __restrict__ tok_w, int* __restrict__ cnt)
{
  const int tid = threadIdx.x;
  const int lane = tid & 63, wid = tid >> 6;
  const int wave_global = blockIdx.x * 4 + wid;     // 0..1023
  const f32x4* __restrict__ Wg1v = (const f32x4*)Wg1;   // [1024][4]
  for (int t = 0; t < N_TOK / 1024; ++t) {
    const int n = wave_global * (N_TOK / 1024) + t;
    double acc[16];
#pragma unroll
    for (int j = 0; j < 16; ++j) acc[j] = 0.0;
    for (int it = 0; it < DIM / 64; ++it) {
      int d = it * 64 + lane;
      double xv = (double)x[(size_t)n * DIM + d];
      f32x4 w0 = Wg1v[(size_t)d * 4 + 0];
      f32x4 w1 = Wg1v[(size_t)d * 4 + 1];
      f32x4 w2 = Wg1v[(size_t)d * 4 + 2];
      f32x4 w3 = Wg1v[(size_t)d * 4 + 3];
#pragma unroll
      for (int q = 0; q < 4; ++q) {
        acc[q]      += xv * (double)w0[q];
        acc[4 + q]  += xv * (double)w1[q];
        acc[8 + q]  += xv * (double)w2[q];
        acc[12 + q] += xv * (double)w3[q];
      }
    }
#pragma unroll
    for (int j = 0; j < 16; ++j) {
#pragma unroll
      for (int s = 32; s > 0; s >>= 1) acc[j] += __shfl_xor(acc[j], s);
    }
    // select acc[lane&15] without dynamic indexing (rule #20)
    const int jl = lane & 15;
    double av = acc[0];
#pragma unroll
    for (int j = 1; j < 16; ++j) av = (jl == j) ? acc[j] : av;
    double tmine = tanh(av);
    const int e = lane & 7;
    double ge = 0.0;
#pragma unroll
    for (int j = 0; j < 16; ++j) {
      double tj = __shfl(tmine, j);
      ge += tj * (double)Wg2[j * 8 + e];
    }
    double m = ge;
#pragma unroll
    for (int s = 1; s < 8; s <<= 1) m = fmax(m, __shfl_xor(m, s));
    double p = exp(ge - m);
    double ssum = p;
#pragma unroll
    for (int s = 1; s < 8; s <<= 1) ssum += __shfl_xor(ssum, s);
    double wsm = p / ssum;
    unsigned long long key =
        (((unsigned long long)__double_as_longlong(wsm)) & ~7ULL) |
        (unsigned long long)(7 - e);
    unsigned long long k1 = key;
#pragma unroll
    for (int s = 1; s < 8; s <<= 1) { unsigned long long o = __shfl_xor(k1, s); k1 = (o > k1) ? o : k1; }
    int e1 = 7 - (int)(k1 & 7ULL);
    unsigned long long k2 = (e == e1) ? 0ULL : key;
#pragma unroll
    for (int s = 1; s < 8; s <<= 1) { unsigned long long o = __shfl_xor(k2, s); k2 = (o > k2) ? o : k2; }
    int e2 = 7 - (int)(k2 & 7ULL);
    double w1v = __longlong_as_double((long long)(k1 & ~7ULL));
    double w2v = __longlong_as_double((long long)(k2 & ~7ULL));
    double inv = 1.0 / (w1v + w2v + 1e-12);
    if (lane == 0) {
      tok_e[2 * n] = e1; tok_e[2 * n + 1] = e2;
      tok_w[2 * n] = (float)(w1v * inv); tok_w[2 * n + 1] = (float)(w2v * inv);
      atomicAdd(&cnt[e1], 1); atomicAdd(&cnt[e2], 1);
    }
  }
}

// offsets padded to multiples of 128 so every 128-row tile is single-expert
__global__ void offsets_kernel(const int* __restrict__ cnt, int* __restrict__ off,
                               int* __restrict__ cur) {
  if (threadIdx.x == 0) {
    int a = 0;
    for (int e = 0; e < NEXP; ++e) {
      off[e] = a; cur[e] = a;
      a += (cnt[e] + 127) & ~127;
    }
    off[NEXP] = a;
  }
}

__global__ __launch_bounds__(256) void scatter_kernel(
    const int* __restrict__ tok_e, const float* __restrict__ tok_w,
    int* __restrict__ cur, int* __restrict__ rows, float* __restrict__ roww,
    int* __restrict__ pair)
{
  int n = blockIdx.x * 256 + threadIdx.x;
  if (n >= N_TOK) return;
#pragma unroll
  for (int k = 0; k < 2; ++k) {
    int e = tok_e[2 * n + k];
    int pos = atomicAdd(&cur[e], 1);
    rows[pos] = n;
    roww[pos] = tok_w[2 * n + k];
    pair[2 * n + k] = pos;
  }
}

// ---------------- fp32 -> fp16 converts ----------------
__global__ __launch_bounds__(256) void convert_x_kernel(
    const float* __restrict__ x, unsigned short* __restrict__ xh)
{
  size_t i = ((size_t)blockIdx.x * 256 + threadIdx.x) * 8;
  f32x4 a = *(const f32x4*)(x + i);
  f32x4 b = *(const f32x4*)(x + i + 4);
  short8 o;
#pragma unroll
  for (int q = 0; q < 4; ++q) { o[q] = (short)f2h(a[q]); o[q + 4] = (short)f2h(b[q]); }
  *(short8*)(xh + i) = o;
}

// transpose+convert: W[e][K][N] fp32 -> Wt[e][N][K] fp16
__global__ __launch_bounds__(256) void wconv_kernel(
    const float* __restrict__ W, unsigned short* __restrict__ Wt,
    const int K, const int N)
{
  __shared__ float t[32][33];
  const int e = blockIdx.z;
  const float* We = W + (size_t)e * K * N;
  unsigned short* Wte = Wt + (size_t)e * K * N;
  const int n0 = blockIdx.x * 32, k0 = blockIdx.y * 32;
  const int tid = threadIdx.x;
  const int r = tid >> 3, c4 = (tid & 7) * 4;
  f32x4 v = *(const f32x4*)(We + (size_t)(k0 + r) * N + n0 + c4);
  t[r][c4 + 0] = v[0]; t[r][c4 + 1] = v[1]; t[r][c4 + 2] = v[2]; t[r][c4 + 3] = v[3];
  __syncthreads();
  u16x4 o;
#pragma unroll
  for (int q = 0; q < 4; ++q) o[q] = f2h(t[c4 + q][r]);
  *(u16x4*)(Wte + (size_t)(n0 + r) * K + k0 + c4) = o;
}

// ---------------- routed GEMM (fp16 MFMA, fp32 acc, coalesced fp16 epilogue) ----
// MODE 0: A = gathered xh rows (via rows[]), out = act1h chunk-local fp16 (acc+bias)
// MODE 1: A = act2 chunk-local,              out = act1h chunk-local fp16 (acc+bias)
// MODE 2: A = act2 chunk-local,              out = d_out atomicAdd f32   [ws fallback]
// MODE 3: A = act2 chunk-local,              out = Y fp16 w*(acc+bias)   [combine later]
template<int MODE>
__global__ __launch_bounds__(256) void gemm_kernel(
    const unsigned short* __restrict__ Abase,
    const unsigned short* __restrict__ Bbase,
    unsigned short* __restrict__ Oh,
    float* __restrict__ Of,
    const float* __restrict__ bias,
    const int* __restrict__ rows,
    const float* __restrict__ roww,
    const int* __restrict__ off,
    const int K, const int N, const int Astride, const int c0, const int lgGX)
{
  // XCD-chunked bijective block remap (m204): consecutive work ids share an XCD's L2
  const unsigned orig = blockIdx.x, nwg = gridDim.x;
  const unsigned q8 = nwg >> 3, r8 = nwg & 7;
  const unsigned xcd = orig & 7, pos = orig >> 3;
  const unsigned wrk = (xcd < r8 ? xcd * (q8 + 1) : r8 * (q8 + 1) + (xcd - r8) * q8) + pos;
  const int tn = (int)(wrk & ((1u << lgGX) - 1u));
  const int rowbase = c0 + (int)(wrk >> lgGX) * 128;

  const int off8 = off[NEXP];
  if (rowbase >= off8) return;
  int e = 0;
  while (e < NEXP - 1 && rowbase >= off[e + 1]) ++e;

  __shared__ __align__(16) unsigned short ldsA[128 * 64];
  __shared__ __align__(16) unsigned short ldsB[128 * 64];
  __shared__ __align__(16) unsigned short ldsT[64 * 136];   // epilogue transpose, +pad

  const int tid = threadIdx.x, lane = tid & 63, wid = tid >> 6;
  const int wm = wid >> 1, wn = wid & 1;
  const int l15 = lane & 15, lh = lane >> 4;

  f32x4 acc[4][4] = {};

  // staging: chunk c = i*256+tid -> LDS bytes c*16 (linear, lane-contiguous per wave)
  // slot (row, s) holds logical k-chunk s^(row&7): pre-swizzled GLOBAL source (T2 both-sides)
  size_t aoff[4], boff[4];
#pragma unroll
  for (int i = 0; i < 4; ++i) {
    int c = i * 256 + tid;
    int row = c >> 3;
    int kc = ((c & 7) ^ (row & 7)) * 8;
    size_t arow;
    if (MODE == 0) arow = (size_t)rows[rowbase + row];
    else           arow = (size_t)(rowbase - c0 + row);
    aoff[i] = arow * (size_t)Astride + kc;
    boff[i] = ((size_t)e * N + (size_t)(tn * 128 + row)) * K + kc;
  }

  for (int k0 = 0; k0 < K; k0 += 64) {
#pragma unroll
    for (int i = 0; i < 4; ++i) {
      int c = i * 256 + tid;
      __builtin_amdgcn_global_load_lds(
          (const __attribute__((address_space(1))) void*)(Abase + aoff[i] + k0),
          (__attribute__((address_space(3))) void*)(ldsA + (size_t)c * 8), 16, 0, 0);
      __builtin_amdgcn_global_load_lds(
          (const __attribute__((address_space(1))) void*)(Bbase + boff[i] + k0),
          (__attribute__((address_space(3))) void*)(ldsB + (size_t)c * 8), 16, 0, 0);
    }
    __syncthreads();
#pragma unroll
    for (int kk = 0; kk < 2; ++kk) {
      short8 af[4], bf[4];
#pragma unroll
      for (int mi = 0; mi < 4; ++mi) {
        int row = wm * 64 + mi * 16 + l15;
        int chunk = (kk * 4 + lh) ^ (row & 7);
        af[mi] = *(const short8*)(ldsA + row * 64 + chunk * 8);
      }
#pragma unroll
      for (int ni = 0; ni < 4; ++ni) {
        int row = wn * 64 + ni * 16 + l15;
        int chunk = (kk * 4 + lh) ^ (row & 7);
        bf[ni] = *(const short8*)(ldsB + row * 64 + chunk * 8);
      }
#pragma unroll
      for (int mi = 0; mi < 4; ++mi)
#pragma unroll
        for (int ni = 0; ni < 4; ++ni)
          acc[mi][ni] = __builtin_amdgcn_mfma_f32_16x16x32_f16(
              __builtin_bit_cast(f16x8, bf[ni]),
              __builtin_bit_cast(f16x8, af[mi]),
              acc[mi][ni], 0, 0, 0);   // D[n][token]: lane holds token=l15, n=lh*4+q
    }
    __syncthreads();
  }

  if (MODE == 2) {
    // fallback: scattered f32 atomics into d_out (only when ws too small)
#pragma unroll
    for (int mi = 0; mi < 4; ++mi) {
      int g = rowbase + wm * 64 + mi * 16 + l15;
      int token = rows[g];
      float wgt = roww[g];
#pragma unroll
      for (int ni = 0; ni < 4; ++ni) {
        int n = tn * 128 + wn * 64 + ni * 16 + lh * 4;
        f32x4 v = acc[mi][ni];
        f32x4 bv = *(const f32x4*)(bias + (size_t)e * N + n);
#pragma unroll
        for (int qd = 0; qd < 4; ++qd)
          atomicAdd(&Of[(size_t)token * N + n + qd], wgt * (v[qd] + bv[qd]));
      }
    }
    return;
  }

  // coalesced fp16 epilogue: fragments -> LDS (64-row halves) -> 256B-run stores
#pragma unroll
  for (int half = 0; half < 2; ++half) {
    if (wm == half) {
#pragma unroll
      for (int mi = 0; mi < 4; ++mi) {
        const int trow = mi * 16 + l15;             // 0..63
        float wgt = 1.0f;
        if (MODE == 3) wgt = roww[rowbase + half * 64 + trow];
#pragma unroll
        for (int ni = 0; ni < 4; ++ni) {
          int ncol = wn * 64 + ni * 16 + lh * 4;    // 0..127 within tile
          f32x4 v = acc[mi][ni];
          f32x4 bv = *(const f32x4*)(bias + (size_t)e * N + tn * 128 + ncol);
          u16x4 h;
#pragma unroll
          for (int qd = 0; qd < 4; ++qd) {
            float vv = v[qd] + bv[qd];
            if (MODE == 3) vv *= wgt;
            h[qd] = f2h(vv);
          }
          *(u16x4*)(ldsT + trow * 136 + ncol) = h;  // stride 136: 2-way bank alias (free)
        }
      }
    }
    __syncthreads();
    const int halfbase = (MODE == 3) ? (rowbase + half * 64)
                                     : (rowbase - c0 + half * 64);
#pragma unroll
    for (int j2 = 0; j2 < 8; ++j2) {
      int flat = j2 * 256 + tid;
      int row = flat >> 5, c8 = flat & 31;          // 32 lanes = 256B contiguous run
      u16x4 v = *(const u16x4*)(ldsT + row * 136 + c8 * 4);
      *(u16x4*)(Oh + (size_t)(halfbase + row) * N + tn * 128 + c8 * 4) = v;
    }
    __syncthreads();
  }
}

// ---------------- LayerNorm + exact GELU: fp16 in, fp16 out (f32 stats) ------
__global__ __launch_bounds__(256) void ln_gelu_kernel(
    const unsigned short* __restrict__ src, unsigned short* __restrict__ dst,
    const float* __restrict__ gam, const float* __restrict__ bet,
    const int* __restrict__ off, const int c0)
{
  const int g = c0 + blockIdx.x;
  if (g >= off[NEXP]) return;
  int e = 0;
  while (e < NEXP - 1 && g >= off[e + 1]) ++e;
  const int tid = threadIdx.x;
  const unsigned short* s0 = src + (size_t)(g - c0) * HID;
  short8 hv = *(const short8*)(s0 + tid * 8);
  float v[8];
  float s = 0.f, sq = 0.f;
#pragma unroll
  for (int q = 0; q < 8; ++q) {
    v[q] = h2f((unsigned short)hv[q]);
    s += v[q]; sq += v[q] * v[q];
  }
#pragma unroll
  for (int sh = 32; sh > 0; sh >>= 1) { s += __shfl_xor(s, sh); sq += __shfl_xor(sq, sh); }
  __shared__ float rs_[4], rq_[4];
  const int lane = tid & 63, wid = tid >> 6;
  if (lane == 0) { rs_[wid] = s; rq_[wid] = sq; }
  __syncthreads();
  s  = rs_[0] + rs_[1] + rs_[2] + rs_[3];
  sq = rq_[0] + rq_[1] + rq_[2] + rq_[3];
  const float mu  = s * (1.0f / HID);
  const float var = sq * (1.0f / HID) - mu * mu;
  const float rstd = rsqrtf(var + 1e-5f);
  const float* gp = gam + (size_t)e * HID + tid * 8;
  const float* bp = bet + (size_t)e * HID + tid * 8;
  short8 o;
#pragma unroll
  for (int q = 0; q < 8; ++q) {
    float t = (v[q] - mu) * rstd * gp[q] + bp[q];
    o[q] = (short)f2h(gelu_exact(t));
  }
  *(short8*)(dst + (size_t)(g - c0) * HID + tid * 8) = o;
}

// ---------------- deterministic 2-row combine (fp16 Y -> f32 out) ------------
__global__ __launch_bounds__(256) void combine_kernel(
    const unsigned short* __restrict__ Y, const int* __restrict__ pair,
    float* __restrict__ out)
{
  const int n = blockIdx.x;
  const int j = threadIdx.x * 4;
  const int r1 = pair[2 * n], r2 = pair[2 * n + 1];
  u16x4 a = *(const u16x4*)(Y + (size_t)r1 * OUTD + j);
  u16x4 b = *(const u16x4*)(Y + (size_t)r2 * OUTD + j);
  f32x4 o;
#pragma unroll
  for (int qd = 0; qd < 4; ++qd) o[qd] = h2f(a[qd]) + h2f(b[qd]);
  *(f32x4*)(out + (size_t)n * OUTD + j) = o;
}

// fallback diagnostic: encode ws_size (MB) into out[0]
__global__ void probe_kernel(float* out, float v) {
  if (threadIdx.x == 0 && blockIdx.x == 0) out[0] = v;
}

extern "C" void kernel_launch(void* const* d_in, const int* in_sizes, int n_in,
                              void* d_out, int out_size, void* d_ws, size_t ws_size,
                              hipStream_t stream) {
  (void)in_sizes; (void)n_in;
  const float* x   = (const float*)d_in[0];
  const float* Wg1 = (const float*)d_in[1];
  const float* Wg2 = (const float*)d_in[2];
  const float* W1  = (const float*)d_in[3];
  const float* b1  = (const float*)d_in[4];
  const float* g1  = (const float*)d_in[5];
  const float* be1 = (const float*)d_in[6];
  const float* W2  = (const float*)d_in[7];
  const float* b2  = (const float*)d_in[8];
  const float* g2  = (const float*)d_in[9];
  const float* be2 = (const float*)d_in[10];
  const float* W3  = (const float*)d_in[11];
  const float* b3  = (const float*)d_in[12];
  float* out = (float*)d_out;

  uint8_t* w = (uint8_t*)d_ws;
  auto alloc = [&](size_t bytes) {
    uint8_t* p = w;
    w += (bytes + 255) & ~(size_t)255;
    return p;
  };
  unsigned short* xh   = (unsigned short*)alloc((size_t)N_TOK * DIM * 2);
  unsigned short* Wt1  = (unsigned short*)alloc((size_t)NEXP * DIM * HID * 2);
  unsigned short* Wt2  = (unsigned short*)alloc((size_t)NEXP * HID * HID * 2);
  unsigned short* Wt3  = (unsigned short*)alloc((size_t)NEXP * HID * OUTD * 2);
  int*   rows  = (int*)alloc((size_t)PADTOT * 4);
  float* roww  = (float*)alloc((size_t)PADTOT * 4);
  int*   tok_e = (int*)alloc((size_t)2 * N_TOK * 4);
  float* tok_w = (float*)alloc((size_t)2 * N_TOK * 4);
  int*   pair  = (int*)alloc((size_t)2 * N_TOK * 4);
  int*   cnt   = (int*)alloc(256);
  int*   off   = (int*)alloc(256);
  int*   cur   = (int*)alloc(256);
  size_t fixed_used = (size_t)(w - (uint8_t*)d_ws);

  // adaptive chunk rows: act1h (fp16) + act2 (fp16) = 8192 B/row
  long long availLL = (long long)ws_size - (long long)fixed_used - 4096;
  int R = 0;
  if (availLL > 0) {
    long long r = availLL / (HID * 2 + HID * 2);
    if (r > PADTOT) r = PADTOT;
    R = (int)(r & ~127LL);
  }
  if (R < 128) {   // diagnostic fallback: out[0] = ws_size in MB
    hipMemsetAsync(d_out, 0, (size_t)out_size * sizeof(float), stream);
    probe_kernel<<<1, 64, 0, stream>>>(out, (float)(ws_size >> 20));
    return;
  }
  unsigned short* act1h = (unsigned short*)alloc((size_t)R * HID * 2);
  unsigned short* act2  = (unsigned short*)alloc((size_t)R * HID * 2);
  const bool single = (R >= PADTOT);   // Y (fp16 [PADTOT][1024]) aliases act1h
  unsigned short* Yh = act1h;

  hipMemsetAsync(cnt, 0, NEXP * sizeof(int), stream);
  hipMemsetAsync(rows, 0, (size_t)PADTOT * 4, stream);   // dummy rows -> token 0
  hipMemsetAsync(roww, 0, (size_t)PADTOT * 4, stream);   // dummy weight -> 0.0
  if (!single)
    hipMemsetAsync(d_out, 0, (size_t)out_size * sizeof(float), stream);  // atomic target

  gate_kernel<<<256, 256, 0, stream>>>(x, Wg1, Wg2, tok_e, tok_w, cnt);
  offsets_kernel<<<1, 64, 0, stream>>>(cnt, off, cur);
  scatter_kernel<<<N_TOK / 256, 256, 0, stream>>>(tok_e, tok_w, cur, rows, roww, pair);

  convert_x_kernel<<<(N_TOK * DIM / 8) / 256, 256, 0, stream>>>(x, xh);
  wconv_kernel<<<dim3(HID / 32, DIM / 32, NEXP), 256, 0, stream>>>(W1, Wt1, DIM, HID);
  wconv_kernel<<<dim3(HID / 32, HID / 32, NEXP), 256, 0, stream>>>(W2, Wt2, HID, HID);
  wconv_kernel<<<dim3(OUTD / 32, HID / 32, NEXP), 256, 0, stream>>>(W3, Wt3, HID, OUTD);

  for (int c0 = 0; c0 < PADTOT; c0 += R) {
    int Rc = PADTOT - c0; if (Rc > R) Rc = R;
    const int yt = Rc / 128;
    gemm_kernel<0><<<16 * yt, 256, 0, stream>>>(xh, Wt1, act1h, nullptr, b1,
                                                rows, roww, off, DIM, HID, DIM, c0, 4);
    ln_gelu_kernel<<<Rc, 256, 0, stream>>>(act1h, act2, g1, be1, off, c0);
    gemm_kernel<1><<<16 * yt, 256, 0, stream>>>(act2, Wt2, act1h, nullptr, b2,
                                                rows, roww, off, HID, HID, HID, c0, 4);
    ln_gelu_kernel<<<Rc, 256, 0, stream>>>(act1h, act2, g2, be2, off, c0);
    if (single)
      gemm_kernel<3><<<8 * yt, 256, 0, stream>>>(act2, Wt3, Yh, nullptr, b3,
                                                 rows, roww, off, HID, OUTD, HID, c0, 3);
    else
      gemm_kernel<2><<<8 * yt, 256, 0, stream>>>(act2, Wt3, nullptr, out, b3,
                                                 rows, roww, off, HID, OUTD, HID, c0, 3);
  }
  if (single)
    combine_kernel<<<N_TOK, 256, 0, stream>>>(Yh, pair, out);
}

// Round 5
// 1936.266 us; speedup vs baseline: 1.4279x; 1.0713x over previous
//
#include <hip/hip_runtime.h>
#include <math.h>
#include <stdint.h>

#define N_TOK 16384
#define DIM   1024
#define NEXP  8
#define HID   2048
#define OUTD  1024
#define PADTOT 34816   // 2*N_TOK + 8*256 : padded compacted-row upper bound (136 tiles of 256)

typedef __attribute__((ext_vector_type(8))) short short8;
typedef __attribute__((ext_vector_type(8))) _Float16 f16x8;
typedef __attribute__((ext_vector_type(4))) float f32x4;
typedef __attribute__((ext_vector_type(4))) unsigned short u16x4;

__device__ __forceinline__ unsigned short f2h(float f) {
  return __builtin_bit_cast(unsigned short, (_Float16)f);   // RNE
}
__device__ __forceinline__ float h2f(unsigned short h) {
  return (float)__builtin_bit_cast(_Float16, h);
}
__device__ __forceinline__ float gelu_exact(float a) {
  return 0.5f * a * (1.0f + erff(a * 0.70710678118654752f));
}

// ---------------- gate: fp64 for routing robustness, no LDS ----------------
__global__ __launch_bounds__(256) void gate_kernel(
    const float* __restrict__ x, const float* __restrict__ Wg1,
    const float* __restrict__ Wg2,
    int* __restrict__ tok_e, float* __restrict__ tok_w, int* __restrict__ cnt)
{
  const int tid = threadIdx.x;
  const int lane = tid & 63, wid = tid >> 6;
  const int wave_global = blockIdx.x * 4 + wid;     // 0..1023
  const f32x4* __restrict__ Wg1v = (const f32x4*)Wg1;   // [1024][4]
  for (int t = 0; t < N_TOK / 1024; ++t) {
    const int n = wave_global * (N_TOK / 1024) + t;
    double acc[16];
#pragma unroll
    for (int j = 0; j < 16; ++j) acc[j] = 0.0;
    for (int it = 0; it < DIM / 64; ++it) {
      int d = it * 64 + lane;
      double xv = (double)x[(size_t)n * DIM + d];
      f32x4 w0 = Wg1v[(size_t)d * 4 + 0];
      f32x4 w1 = Wg1v[(size_t)d * 4 + 1];
      f32x4 w2 = Wg1v[(size_t)d * 4 + 2];
      f32x4 w3 = Wg1v[(size_t)d * 4 + 3];
#pragma unroll
      for (int q = 0; q < 4; ++q) {
        acc[q]      += xv * (double)w0[q];
        acc[4 + q]  += xv * (double)w1[q];
        acc[8 + q]  += xv * (double)w2[q];
        acc[12 + q] += xv * (double)w3[q];
      }
    }
#pragma unroll
    for (int j = 0; j < 16; ++j) {
#pragma unroll
      for (int s = 32; s > 0; s >>= 1) acc[j] += __shfl_xor(acc[j], s);
    }
    const int jl = lane & 15;
    double av = acc[0];
#pragma unroll
    for (int j = 1; j < 16; ++j) av = (jl == j) ? acc[j] : av;
    double tmine = tanh(av);
    const int e = lane & 7;
    double ge = 0.0;
#pragma unroll
    for (int j = 0; j < 16; ++j) {
      double tj = __shfl(tmine, j);
      ge += tj * (double)Wg2[j * 8 + e];
    }
    double m = ge;
#pragma unroll
    for (int s = 1; s < 8; s <<= 1) m = fmax(m, __shfl_xor(m, s));
    double p = exp(ge - m);
    double ssum = p;
#pragma unroll
    for (int s = 1; s < 8; s <<= 1) ssum += __shfl_xor(ssum, s);
    double wsm = p / ssum;
    unsigned long long key =
        (((unsigned long long)__double_as_longlong(wsm)) & ~7ULL) |
        (unsigned long long)(7 - e);
    unsigned long long k1 = key;
#pragma unroll
    for (int s = 1; s < 8; s <<= 1) { unsigned long long o = __shfl_xor(k1, s); k1 = (o > k1) ? o : k1; }
    int e1 = 7 - (int)(k1 & 7ULL);
    unsigned long long k2 = (e == e1) ? 0ULL : key;
#pragma unroll
    for (int s = 1; s < 8; s <<= 1) { unsigned long long o = __shfl_xor(k2, s); k2 = (o > k2) ? o : k2; }
    int e2 = 7 - (int)(k2 & 7ULL);
    double w1v = __longlong_as_double((long long)(k1 & ~7ULL));
    double w2v = __longlong_as_double((long long)(k2 & ~7ULL));
    double inv = 1.0 / (w1v + w2v + 1e-12);
    if (lane == 0) {
      tok_e[2 * n] = e1; tok_e[2 * n + 1] = e2;
      tok_w[2 * n] = (float)(w1v * inv); tok_w[2 * n + 1] = (float)(w2v * inv);
      atomicAdd(&cnt[e1], 1); atomicAdd(&cnt[e2], 1);
    }
  }
}

// offsets padded to multiples of 256 so every 256-row tile is single-expert
__global__ void offsets_kernel(const int* __restrict__ cnt, int* __restrict__ off,
                               int* __restrict__ cur) {
  if (threadIdx.x == 0) {
    int a = 0;
    for (int e = 0; e < NEXP; ++e) {
      off[e] = a; cur[e] = a;
      a += (cnt[e] + 255) & ~255;
    }
    off[NEXP] = a;
  }
}

__global__ __launch_bounds__(256) void scatter_kernel(
    const int* __restrict__ tok_e, const float* __restrict__ tok_w,
    int* __restrict__ cur, int* __restrict__ rows, float* __restrict__ roww,
    int* __restrict__ pair)
{
  int n = blockIdx.x * 256 + threadIdx.x;
  if (n >= N_TOK) return;
#pragma unroll
  for (int k = 0; k < 2; ++k) {
    int e = tok_e[2 * n + k];
    int pos = atomicAdd(&cur[e], 1);
    rows[pos] = n;
    roww[pos] = tok_w[2 * n + k];
    pair[2 * n + k] = pos;
  }
}

// ---------------- fp32 -> fp16 converts ----------------
__global__ __launch_bounds__(256) void convert_x_kernel(
    const float* __restrict__ x, unsigned short* __restrict__ xh)
{
  size_t i = ((size_t)blockIdx.x * 256 + threadIdx.x) * 8;
  f32x4 a = *(const f32x4*)(x + i);
  f32x4 b = *(const f32x4*)(x + i + 4);
  short8 o;
#pragma unroll
  for (int q = 0; q < 4; ++q) { o[q] = (short)f2h(a[q]); o[q + 4] = (short)f2h(b[q]); }
  *(short8*)(xh + i) = o;
}

// transpose+convert: W[e][K][N] fp32 -> Wt[e][N][K] fp16
__global__ __launch_bounds__(256) void wconv_kernel(
    const float* __restrict__ W, unsigned short* __restrict__ Wt,
    const int K, const int N)
{
  __shared__ float t[32][33];
  const int e = blockIdx.z;
  const float* We = W + (size_t)e * K * N;
  unsigned short* Wte = Wt + (size_t)e * K * N;
  const int n0 = blockIdx.x * 32, k0 = blockIdx.y * 32;
  const int tid = threadIdx.x;
  const int r = tid >> 3, c4 = (tid & 7) * 4;
  f32x4 v = *(const f32x4*)(We + (size_t)(k0 + r) * N + n0 + c4);
  t[r][c4 + 0] = v[0]; t[r][c4 + 1] = v[1]; t[r][c4 + 2] = v[2]; t[r][c4 + 3] = v[3];
  __syncthreads();
  u16x4 o;
#pragma unroll
  for (int q = 0; q < 4; ++q) o[q] = f2h(t[c4 + q][r]);
  *(u16x4*)(Wte + (size_t)(n0 + r) * K + k0 + c4) = o;
}

// ============ 256x256 8-wave 8-phase routed GEMM (fp16 MFMA, fp32 acc) ============
// Per K-tile (BK=64) 4 quadrant-phases; staging at quarter granularity into dying
// LDS sub-slots; counted vmcnt {6,10,-,8}; raw s_barrier; setprio around MFMA.
// MODE 0: A = gathered xh rows, out = act1h (acc+bias)
// MODE 1: A = act2,             out = act1h (acc+bias)
// MODE 2: A = act2,             out = d_out atomicAdd f32 (ws-too-small fallback)
// MODE 3: A = act2,             out = Y fp16 w*(acc+bias)

#define STAGE_A(SB, QM, T) do {                                               \
  _Pragma("unroll") for (int i_ = 0; i_ < 2; ++i_)                            \
    __builtin_amdgcn_global_load_lds(                                         \
      (const __attribute__((address_space(1))) void*)(Abase + aoff[QM][i_] + (size_t)(T)*64 + kc8), \
      (__attribute__((address_space(3))) void*)(lds + (SB)*16384 + (QM)*4096 + i_*8192 + tid*8), \
      16, 0, 0);                                                              \
} while (0)

#define STAGE_B(SB, QN, T) do {                                               \
  _Pragma("unroll") for (int i_ = 0; i_ < 2; ++i_)                            \
    __builtin_amdgcn_global_load_lds(                                         \
      (const __attribute__((address_space(1))) void*)(Bbase + boff[QN][i_] + (size_t)(T)*64 + kc8), \
      (__attribute__((address_space(3))) void*)(lds + 32768 + (SB)*16384 + (QN)*2048 + bdst[i_]), \
      16, 0, 0);                                                              \
} while (0)

// quadrant (QM,QN): 12 ds_read_b128 -> mid barrier -> 16 MFMA (setprio-wrapped)
#define QUAD(QM, QN) do {                                                     \
    short8 af[4][2], bf[2][2];                                                \
    _Pragma("unroll") for (int mi = 0; mi < 4; ++mi)                          \
    _Pragma("unroll") for (int kk = 0; kk < 2; ++kk) {                        \
      const int row_ = wm*128 + (QM)*64 + mi*16 + l15;                        \
      const int ch_ = ((kk*4 + lh) ^ (row_ & 7));                             \
      af[mi][kk] = *(const short8*)(ldsAb + row_*64 + ch_*8);                 \
    }                                                                         \
    _Pragma("unroll") for (int ni = 0; ni < 2; ++ni)                          \
    _Pragma("unroll") for (int kk = 0; kk < 2; ++kk) {                        \
      const int row_ = wn*64 + (QN)*32 + ni*16 + l15;                         \
      const int ch_ = ((kk*4 + lh) ^ (row_ & 7));                             \
      bf[ni][kk] = *(const short8*)(ldsBb + row_*64 + ch_*8);                 \
    }                                                                         \
    asm volatile("s_barrier" ::: "memory");                                   \
    __builtin_amdgcn_s_setprio(1);                                            \
    _Pragma("unroll") for (int kk = 0; kk < 2; ++kk)                          \
    _Pragma("unroll") for (int mi = 0; mi < 4; ++mi)                          \
    _Pragma("unroll") for (int ni = 0; ni < 2; ++ni)                          \
      acc[(QM)*4 + mi][(QN)*2 + ni] = __builtin_amdgcn_mfma_f32_16x16x32_f16( \
          __builtin_bit_cast(f16x8, bf[ni][kk]),                              \
          __builtin_bit_cast(f16x8, af[mi][kk]),                              \
          acc[(QM)*4 + mi][(QN)*2 + ni], 0, 0, 0);                            \
    __builtin_amdgcn_s_setprio(0);                                            \
} while (0)

#define PH_END(N_) do { asm volatile("s_waitcnt vmcnt(" #N_ ")" ::: "memory"); \
                        asm volatile("s_barrier" ::: "memory"); } while (0)

template<int MODE>
__global__ __launch_bounds__(512, 1) void gemm256_kernel(
    const unsigned short* __restrict__ Abase,
    const unsigned short* __restrict__ Bbase,
    unsigned short* __restrict__ Oh,
    float* __restrict__ Of,
    const float* __restrict__ bias,
    const int* __restrict__ rows,
    const float* __restrict__ roww,
    const int* __restrict__ off,
    const int K, const int N, const int Astride, const int c0, const int lgGX)
{
  // XCD-chunked bijective block remap (m204)
  const unsigned orig = blockIdx.x, nwg = gridDim.x;
  const unsigned q8 = nwg >> 3, r8 = nwg & 7;
  const unsigned xcd = orig & 7, pos = orig >> 3;
  const unsigned wrk = (xcd < r8 ? xcd * (q8 + 1) : r8 * (q8 + 1) + (xcd - r8) * q8) + pos;
  const int tn = (int)(wrk & ((1u << lgGX) - 1u));
  const int rowbase = c0 + (int)(wrk >> lgGX) * 256;

  const int off8 = off[NEXP];
  if (rowbase >= off8) return;
  int e = 0;
  while (e < NEXP - 1 && rowbase >= off[e + 1]) ++e;

  // LDS: A[2 buf][256][64] fp16 @0, B[2 buf][256][64] fp16 @32768 shorts = 128 KiB
  __shared__ __align__(16) unsigned short lds[65536];

  const int tid = threadIdx.x, lane = tid & 63, wid = tid >> 6;
  const int wm = wid >> 2, wn = wid & 3;       // 2 x 4 waves, each owns 128x64
  const int l15 = lane & 15, lh = lane >> 4;
  const int kc8 = ((tid & 7) ^ ((tid >> 3) & 7)) * 8;   // pre-swizzled source chunk

  f32x4 acc[8][4] = {};

  // per-thread staging offsets (element units)
  size_t aoff[2][2];
#pragma unroll
  for (int qm = 0; qm < 2; ++qm)
#pragma unroll
    for (int i = 0; i < 2; ++i) {
      int grow = rowbase + i * 128 + qm * 64 + (tid >> 3);
      size_t arow = (MODE == 0) ? (size_t)rows[grow] : (size_t)(grow - c0);
      aoff[qm][i] = arow * (size_t)Astride;
    }
  size_t boff[2][2];
#pragma unroll
  for (int qn = 0; qn < 2; ++qn)
#pragma unroll
    for (int i = 0; i < 2; ++i) {
      int rl = i * 64 + (tid >> 3);
      int brow = (rl >> 5) * 64 + qn * 32 + (rl & 31);
      boff[qn][i] = ((size_t)e * N + (size_t)(tn * 256 + brow)) * (size_t)K;
    }
  int bdst[2];
#pragma unroll
  for (int i = 0; i < 2; ++i)
    bdst[i] = (i * 2 + (tid >> 8)) * 4096 + (tid & 255) * 8;

  const int nt = K >> 6;
  // prologue: issue stream [t0.Bq0, t0.Aq0, t0.Bq1, t0.Aq1, t1.Bq0, t1.Aq0]
  STAGE_B(0, 0, 0); STAGE_A(0, 0, 0); STAGE_B(0, 1, 0); STAGE_A(0, 1, 0);
  STAGE_B(1, 0, 1); STAGE_A(1, 0, 1);
  PH_END(8);   // t0.Bq0/Aq0 done (8 newer loads outstanding)

  for (int t = 0; t < nt; ++t) {
    const int b = t & 1;
    const bool tw = (t + 2 >= nt);               // tail: drain instead of counted
    const unsigned short* ldsAb = lds + b * 16384;
    const unsigned short* ldsBb = lds + 32768 + b * 16384;
    // ph0: quadrant (0,0); stage (t+1).Bq1 -> buf b^1
    if (t + 1 < nt) STAGE_B(b ^ 1, 1, t + 1);
    QUAD(0, 0);
    if (tw) PH_END(0); else PH_END(6);           // guards ph1's need: t.Aq1
    // ph1: (1,0); stage (t+1).Aq1 -> buf b^1
    if (t + 1 < nt) STAGE_A(b ^ 1, 1, t + 1);
    QUAD(1, 0);
    if (tw) PH_END(0); else PH_END(10);          // guards ph2's need: t.Bq1
    // ph2: (0,1); stage (t+2).Bq0 -> buf b (t's Bq0 dead after ph1)
    if (t + 2 < nt) STAGE_B(b, 0, t + 2);
    QUAD(0, 1);
    asm volatile("s_barrier" ::: "memory");      // ph3 needs nothing new
    // ph3: (1,1); stage (t+2).Aq0 -> buf b (t's Aq0 dead after ph2)
    if (t + 2 < nt) STAGE_A(b, 0, t + 2);
    QUAD(1, 1);
    if (tw) PH_END(0); else PH_END(8);           // guards (t+1).ph0: (t+1).Aq0/Bq0
  }

  if (MODE == 2) {
    // fallback: scattered f32 atomics into d_out
#pragma unroll
    for (int mi = 0; mi < 8; ++mi) {
      int g = rowbase + wm * 128 + mi * 16 + l15;
      int token = rows[g];
      float wgt = roww[g];
#pragma unroll
      for (int ni = 0; ni < 4; ++ni) {
        int n = tn * 256 + wn * 64 + ni * 16 + lh * 4;
        f32x4 v = acc[mi][ni];
        f32x4 bv = *(const f32x4*)(bias + (size_t)e * N + n);
#pragma unroll
        for (int qd = 0; qd < 4; ++qd)
          atomicAdd(&Of[(size_t)token * N + n + qd], wgt * (v[qd] + bv[qd]));
      }
    }
    return;
  }

  // epilogue: acc -> swizzled fp16 tile in LDS (reuse staging LDS) -> coalesced stores
  __syncthreads();
#pragma unroll
  for (int mi = 0; mi < 8; ++mi) {
    const int row = wm * 128 + mi * 16 + l15;
    float wgt = 1.0f;
    if (MODE == 3) wgt = roww[rowbase + row];
#pragma unroll
    for (int ni = 0; ni < 4; ++ni) {
      const int col = wn * 64 + ni * 16 + lh * 4;
      f32x4 v = acc[mi][ni];
      f32x4 bv = *(const f32x4*)(bias + (size_t)e * N + tn * 256 + col);
      u16x4 h;
#pragma unroll
      for (int qd = 0; qd < 4; ++qd) {
        float vv = v[qd] + bv[qd];
        if (MODE == 3) vv *= wgt;
        h[qd] = f2h(vv);
      }
      const int ch = (col >> 3) ^ (row & 7);
      *(u16x4*)(lds + row * 256 + ch * 8 + (col & 7)) = h;
    }
  }
  __syncthreads();
#pragma unroll
  for (int it = 0; it < 16; ++it) {
    const int flat = it * 512 + tid;
    const int row = flat >> 5;              // 0..255
    const int ch = flat & 31;               // 32 x 16B = full 512B row
    const int chs = ch ^ (row & 7);
    short8 v = *(const short8*)(lds + row * 256 + chs * 8);
    const int g = rowbase + row;
    unsigned short* dst = (MODE == 3) ? (Oh + (size_t)g * N)
                                      : (Oh + (size_t)(g - c0) * N);
    *(short8*)(dst + tn * 256 + ch * 8) = v;
  }
}

// ---------------- LayerNorm + exact GELU: fp16 in, fp16 out (f32 stats) ------
__global__ __launch_bounds__(256) void ln_gelu_kernel(
    const unsigned short* __restrict__ src, unsigned short* __restrict__ dst,
    const float* __restrict__ gam, const float* __restrict__ bet,
    const int* __restrict__ off, const int c0)
{
  const int g = c0 + blockIdx.x;
  if (g >= off[NEXP]) return;
  int e = 0;
#pragma unroll
  for (int q = 1; q < NEXP; ++q) if (g >= off[q]) e = q;
  const int tid = threadIdx.x;
  const unsigned short* s0 = src + (size_t)(g - c0) * HID;
  short8 hv = *(const short8*)(s0 + tid * 8);
  float v[8];
  float s = 0.f, sq = 0.f;
#pragma unroll
  for (int q = 0; q < 8; ++q) {
    v[q] = h2f((unsigned short)hv[q]);
    s += v[q]; sq += v[q] * v[q];
  }
#pragma unroll
  for (int sh = 32; sh > 0; sh >>= 1) { s += __shfl_xor(s, sh); sq += __shfl_xor(sq, sh); }
  __shared__ float rs_[4], rq_[4];
  const int lane = tid & 63, wid = tid >> 6;
  if (lane == 0) { rs_[wid] = s; rq_[wid] = sq; }
  __syncthreads();
  s  = rs_[0] + rs_[1] + rs_[2] + rs_[3];
  sq = rq_[0] + rq_[1] + rq_[2] + rq_[3];
  const float mu  = s * (1.0f / HID);
  const float var = sq * (1.0f / HID) - mu * mu;
  const float rstd = rsqrtf(var + 1e-5f);
  const float* gp = gam + (size_t)e * HID + tid * 8;
  const float* bp = bet + (size_t)e * HID + tid * 8;
  short8 o;
#pragma unroll
  for (int q = 0; q < 8; ++q) {
    float t = (v[q] - mu) * rstd * gp[q] + bp[q];
    o[q] = (short)f2h(gelu_exact(t));
  }
  *(short8*)(dst + (size_t)(g - c0) * HID + tid * 8) = o;
}

// ---------------- deterministic 2-row combine (fp16 Y -> f32 out) ------------
__global__ __launch_bounds__(256) void combine_kernel(
    const unsigned short* __restrict__ Y, const int* __restrict__ pair,
    float* __restrict__ out)
{
  const int n = blockIdx.x;
  const int j = threadIdx.x * 4;
  const int r1 = pair[2 * n], r2 = pair[2 * n + 1];
  u16x4 a = *(const u16x4*)(Y + (size_t)r1 * OUTD + j);
  u16x4 b = *(const u16x4*)(Y + (size_t)r2 * OUTD + j);
  f32x4 o;
#pragma unroll
  for (int qd = 0; qd < 4; ++qd) o[qd] = h2f(a[qd]) + h2f(b[qd]);
  *(f32x4*)(out + (size_t)n * OUTD + j) = o;
}

// fallback diagnostic: encode ws_size (MB) into out[0]
__global__ void probe_kernel(float* out, float v) {
  if (threadIdx.x == 0 && blockIdx.x == 0) out[0] = v;
}

extern "C" void kernel_launch(void* const* d_in, const int* in_sizes, int n_in,
                              void* d_out, int out_size, void* d_ws, size_t ws_size,
                              hipStream_t stream) {
  (void)in_sizes; (void)n_in;
  const float* x   = (const float*)d_in[0];
  const float* Wg1 = (const float*)d_in[1];
  const float* Wg2 = (const float*)d_in[2];
  const float* W1  = (const float*)d_in[3];
  const float* b1  = (const float*)d_in[4];
  const float* g1  = (const float*)d_in[5];
  const float* be1 = (const float*)d_in[6];
  const float* W2  = (const float*)d_in[7];
  const float* b2  = (const float*)d_in[8];
  const float* g2  = (const float*)d_in[9];
  const float* be2 = (const float*)d_in[10];
  const float* W3  = (const float*)d_in[11];
  const float* b3  = (const float*)d_in[12];
  float* out = (float*)d_out;

  uint8_t* w = (uint8_t*)d_ws;
  auto alloc = [&](size_t bytes) {
    uint8_t* p = w;
    w += (bytes + 255) & ~(size_t)255;
    return p;
  };
  unsigned short* xh   = (unsigned short*)alloc((size_t)N_TOK * DIM * 2);
  unsigned short* Wt1  = (unsigned short*)alloc((size_t)NEXP * DIM * HID * 2);
  unsigned short* Wt2  = (unsigned short*)alloc((size_t)NEXP * HID * HID * 2);
  unsigned short* Wt3  = (unsigned short*)alloc((size_t)NEXP * HID * OUTD * 2);
  int*   rows  = (int*)alloc((size_t)PADTOT * 4);
  float* roww  = (float*)alloc((size_t)PADTOT * 4);
  int*   tok_e = (int*)alloc((size_t)2 * N_TOK * 4);
  float* tok_w = (float*)alloc((size_t)2 * N_TOK * 4);
  int*   pair  = (int*)alloc((size_t)2 * N_TOK * 4);
  int*   cnt   = (int*)alloc(256);
  int*   off   = (int*)alloc(256);
  int*   cur   = (int*)alloc(256);
  size_t fixed_used = (size_t)(w - (uint8_t*)d_ws);

  // adaptive chunk rows: act1h (fp16) + act2 (fp16) = 8192 B/row, 256-row granules
  long long availLL = (long long)ws_size - (long long)fixed_used - 4096;
  int R = 0;
  if (availLL > 0) {
    long long r = availLL / (HID * 2 + HID * 2);
    if (r > PADTOT) r = PADTOT;
    R = (int)(r & ~255LL);
  }
  if (R < 256) {   // diagnostic fallback: out[0] = ws_size in MB
    hipMemsetAsync(d_out, 0, (size_t)out_size * sizeof(float), stream);
    probe_kernel<<<1, 64, 0, stream>>>(out, (float)(ws_size >> 20));
    return;
  }
  unsigned short* act1h = (unsigned short*)alloc((size_t)R * HID * 2);
  unsigned short* act2  = (unsigned short*)alloc((size_t)R * HID * 2);
  const bool single = (R >= PADTOT);   // Y (fp16 [PADTOT][1024]) aliases act1h
  unsigned short* Yh = act1h;

  hipMemsetAsync(cnt, 0, NEXP * sizeof(int), stream);
  hipMemsetAsync(rows, 0, (size_t)PADTOT * 4, stream);   // dummy rows -> token 0
  hipMemsetAsync(roww, 0, (size_t)PADTOT * 4, stream);   // dummy weight -> 0.0
  if (!single)
    hipMemsetAsync(d_out, 0, (size_t)out_size * sizeof(float), stream);  // atomic target

  gate_kernel<<<256, 256, 0, stream>>>(x, Wg1, Wg2, tok_e, tok_w, cnt);
  offsets_kernel<<<1, 64, 0, stream>>>(cnt, off, cur);
  scatter_kernel<<<N_TOK / 256, 256, 0, stream>>>(tok_e, tok_w, cur, rows, roww, pair);

  convert_x_kernel<<<(N_TOK * DIM / 8) / 256, 256, 0, stream>>>(x, xh);
  wconv_kernel<<<dim3(HID / 32, DIM / 32, NEXP), 256, 0, stream>>>(W1, Wt1, DIM, HID);
  wconv_kernel<<<dim3(HID / 32, HID / 32, NEXP), 256, 0, stream>>>(W2, Wt2, HID, HID);
  wconv_kernel<<<dim3(OUTD / 32, HID / 32, NEXP), 256, 0, stream>>>(W3, Wt3, HID, OUTD);

  for (int c0 = 0; c0 < PADTOT; c0 += R) {
    int Rc = PADTOT - c0; if (Rc > R) Rc = R;
    const int yt = Rc / 256;
    gemm256_kernel<0><<<8 * yt, 512, 0, stream>>>(xh, Wt1, act1h, nullptr, b1,
                                                  rows, roww, off, DIM, HID, DIM, c0, 3);
    ln_gelu_kernel<<<Rc, 256, 0, stream>>>(act1h, act2, g1, be1, off, c0);
    gemm256_kernel<1><<<8 * yt, 512, 0, stream>>>(act2, Wt2, act1h, nullptr, b2,
                                                  rows, roww, off, HID, HID, HID, c0, 3);
    ln_gelu_kernel<<<Rc, 256, 0, stream>>>(act1h, act2, g2, be2, off, c0);
    if (single)
      gemm256_kernel<3><<<4 * yt, 512, 0, stream>>>(act2, Wt3, Yh, nullptr, b3,
                                                    rows, roww, off, HID, OUTD, HID, c0, 2);
    else
      gemm256_kernel<2><<<4 * yt, 512, 0, stream>>>(act2, Wt3, nullptr, out, b3,
                                                    rows, roww, off, HID, OUTD, HID, c0, 2);
  }
  if (single)
    combine_kernel<<<N_TOK, 256, 0, stream>>>(Yh, pair, out);
}

// Round 6
// 1903.770 us; speedup vs baseline: 1.4523x; 1.0171x over previous
//
#include <hip/hip_runtime.h>
#include <math.h>
#include <stdint.h>

#define N_TOK 16384
#define DIM   1024
#define NEXP  8
#define HID   2048
#define OUTD  1024
#define PADTOT 34816   // 2*N_TOK + 8*256 : padded compacted-row upper bound (136 tiles of 256)

typedef __attribute__((ext_vector_type(8))) short short8;
typedef __attribute__((ext_vector_type(8))) _Float16 f16x8;
typedef __attribute__((ext_vector_type(4))) float f32x4;
typedef __attribute__((ext_vector_type(4))) unsigned short u16x4;

__device__ __forceinline__ unsigned short f2h(float f) {
  return __builtin_bit_cast(unsigned short, (_Float16)f);   // RNE
}
__device__ __forceinline__ float h2f(unsigned short h) {
  return (float)__builtin_bit_cast(_Float16, h);
}
__device__ __forceinline__ float gelu_exact(float a) {
  return 0.5f * a * (1.0f + erff(a * 0.70710678118654752f));
}

// ---------------- gate: fp64 math, high-TLP structure ----------------
// 2048 blocks x 256 thr; 8 tokens/block; Wg1 rows register-cached across tokens.
__global__ __launch_bounds__(256) void gate_kernel(
    const float* __restrict__ x, const float* __restrict__ Wg1,
    const float* __restrict__ Wg2,
    int* __restrict__ tok_e, float* __restrict__ tok_w, int* __restrict__ cnt)
{
  const int tid = threadIdx.x;
  const int lane = tid & 63, wid = tid >> 6;
  const f32x4* __restrict__ Wg1v = (const f32x4*)Wg1;   // [1024][4xf32x4]
  // register-cache my 4 rows of Wg1 (d = tid + 256*i), 16 f32 each -> 16 VGPR
  f32x4 wreg[4][4];
#pragma unroll
  for (int i = 0; i < 4; ++i)
#pragma unroll
    for (int c = 0; c < 4; ++c)
      wreg[i][c] = Wg1v[(size_t)(tid + 256 * i) * 4 + c];

  __shared__ double red[4 * 16];

  for (int tk = 0; tk < 8; ++tk) {
    const int n = blockIdx.x * 8 + tk;
    // coalesced x loads: thread covers d = tid + 256*i
    double xv[4];
#pragma unroll
    for (int i = 0; i < 4; ++i)
      xv[i] = (double)x[(size_t)n * DIM + tid + 256 * i];
    double acc[16];
#pragma unroll
    for (int j = 0; j < 16; ++j) acc[j] = 0.0;
#pragma unroll
    for (int i = 0; i < 4; ++i)
#pragma unroll
      for (int c = 0; c < 4; ++c)
#pragma unroll
        for (int q = 0; q < 4; ++q)
          acc[c * 4 + q] += xv[i] * (double)wreg[i][c][q];
    // wave reduction of 16 accumulators
#pragma unroll
    for (int j = 0; j < 16; ++j)
#pragma unroll
      for (int s = 32; s > 0; s >>= 1) acc[j] += __shfl_xor(acc[j], s);
    if (lane == 0) {
#pragma unroll
      for (int j = 0; j < 16; ++j) red[wid * 16 + j] = acc[j];
    }
    __syncthreads();
    if (wid == 0) {
      // lane j (<16) finalizes logit j; others idle-safe
      double t = 0.0;
      if (lane < 16) {
        t = red[lane] + red[16 + lane] + red[32 + lane] + red[48 + lane];
        t = tanh(t);
      }
      const int e = lane & 7;
      double ge = 0.0;
#pragma unroll
      for (int j = 0; j < 16; ++j) {
        double tj = __shfl(t, j);
        ge += tj * (double)Wg2[j * 8 + e];
      }
      // softmax over 8 within each 8-lane group
      double m = ge;
#pragma unroll
      for (int s = 1; s < 8; s <<= 1) m = fmax(m, __shfl_xor(m, s));
      double p = exp(ge - m);
      double ssum = p;
#pragma unroll
      for (int s = 1; s < 8; s <<= 1) ssum += __shfl_xor(ssum, s);
      double wsm = p / ssum;
      // top-2 via 64-bit keys (ties -> lowest index, like lax.top_k)
      unsigned long long key =
          (((unsigned long long)__double_as_longlong(wsm)) & ~7ULL) |
          (unsigned long long)(7 - e);
      unsigned long long k1 = key;
#pragma unroll
      for (int s = 1; s < 8; s <<= 1) { unsigned long long o = __shfl_xor(k1, s); k1 = (o > k1) ? o : k1; }
      int e1 = 7 - (int)(k1 & 7ULL);
      unsigned long long k2 = (e == e1) ? 0ULL : key;
#pragma unroll
      for (int s = 1; s < 8; s <<= 1) { unsigned long long o = __shfl_xor(k2, s); k2 = (o > k2) ? o : k2; }
      int e2 = 7 - (int)(k2 & 7ULL);
      double w1v = __longlong_as_double((long long)(k1 & ~7ULL));
      double w2v = __longlong_as_double((long long)(k2 & ~7ULL));
      double inv = 1.0 / (w1v + w2v + 1e-12);
      if (lane == 0) {
        tok_e[2 * n] = e1; tok_e[2 * n + 1] = e2;
        tok_w[2 * n] = (float)(w1v * inv); tok_w[2 * n + 1] = (float)(w2v * inv);
        atomicAdd(&cnt[e1], 1); atomicAdd(&cnt[e2], 1);
      }
    }
    __syncthreads();
  }
}

// offsets padded to multiples of 256 so every 256-row tile is single-expert
__global__ void offsets_kernel(const int* __restrict__ cnt, int* __restrict__ off,
                               int* __restrict__ cur) {
  if (threadIdx.x == 0) {
    int a = 0;
    for (int e = 0; e < NEXP; ++e) {
      off[e] = a; cur[e] = a;
      a += (cnt[e] + 255) & ~255;
    }
    off[NEXP] = a;
  }
}

__global__ __launch_bounds__(256) void scatter_kernel(
    const int* __restrict__ tok_e, const float* __restrict__ tok_w,
    int* __restrict__ cur, int* __restrict__ rows, float* __restrict__ roww,
    int* __restrict__ pair)
{
  int n = blockIdx.x * 256 + threadIdx.x;
  if (n >= N_TOK) return;
#pragma unroll
  for (int k = 0; k < 2; ++k) {
    int e = tok_e[2 * n + k];
    int pos = atomicAdd(&cur[e], 1);
    rows[pos] = n;
    roww[pos] = tok_w[2 * n + k];
    pair[2 * n + k] = pos;
  }
}

// ---------------- fp32 -> fp16 converts ----------------
__global__ __launch_bounds__(256) void convert_x_kernel(
    const float* __restrict__ x, unsigned short* __restrict__ xh)
{
  size_t i = ((size_t)blockIdx.x * 256 + threadIdx.x) * 8;
  f32x4 a = *(const f32x4*)(x + i);
  f32x4 b = *(const f32x4*)(x + i + 4);
  short8 o;
#pragma unroll
  for (int q = 0; q < 4; ++q) { o[q] = (short)f2h(a[q]); o[q + 4] = (short)f2h(b[q]); }
  *(short8*)(xh + i) = o;
}

// transpose+convert: W[e][K][N] fp32 -> Wt[e][N][K] fp16
__global__ __launch_bounds__(256) void wconv_kernel(
    const float* __restrict__ W, unsigned short* __restrict__ Wt,
    const int K, const int N)
{
  __shared__ float t[32][33];
  const int e = blockIdx.z;
  const float* We = W + (size_t)e * K * N;
  unsigned short* Wte = Wt + (size_t)e * K * N;
  const int n0 = blockIdx.x * 32, k0 = blockIdx.y * 32;
  const int tid = threadIdx.x;
  const int r = tid >> 3, c4 = (tid & 7) * 4;
  f32x4 v = *(const f32x4*)(We + (size_t)(k0 + r) * N + n0 + c4);
  t[r][c4 + 0] = v[0]; t[r][c4 + 1] = v[1]; t[r][c4 + 2] = v[2]; t[r][c4 + 3] = v[3];
  __syncthreads();
  u16x4 o;
#pragma unroll
  for (int q = 0; q < 4; ++q) o[q] = f2h(t[c4 + q][r]);
  *(u16x4*)(Wte + (size_t)(n0 + r) * K + k0 + c4) = o;
}

// ============ 256x256 8-wave 8-phase routed GEMM (fp16 MFMA, fp32 acc) ============
// Per K-tile (BK=64) 4 quadrant-phases; staging at quarter granularity into dying
// LDS sub-slots; counted vmcnt {6,10,-,8}; raw s_barrier; setprio around MFMA.
// MODE 0: A = gathered xh rows, out = act1h (acc+bias)
// MODE 1: A = act2,             out = act1h (acc+bias)
// MODE 2: A = act2,             out = d_out atomicAdd f32 (ws-too-small fallback)
// MODE 3: A = act2,             out = Y fp16 w*(acc+bias)

#define STAGE_A(SB, QM, T) do {                                               \
  _Pragma("unroll") for (int i_ = 0; i_ < 2; ++i_)                            \
    __builtin_amdgcn_global_load_lds(                                         \
      (const __attribute__((address_space(1))) void*)(Abase + aoff[QM][i_] + (size_t)(T)*64 + kc8), \
      (__attribute__((address_space(3))) void*)(lds + (SB)*16384 + (QM)*4096 + i_*8192 + tid*8), \
      16, 0, 0);                                                              \
} while (0)

#define STAGE_B(SB, QN, T) do {                                               \
  _Pragma("unroll") for (int i_ = 0; i_ < 2; ++i_)                            \
    __builtin_amdgcn_global_load_lds(                                         \
      (const __attribute__((address_space(1))) void*)(Bbase + boff[QN][i_] + (size_t)(T)*64 + kc8), \
      (__attribute__((address_space(3))) void*)(lds + 32768 + (SB)*16384 + (QN)*2048 + bdst[i_]), \
      16, 0, 0);                                                              \
} while (0)

// quadrant (QM,QN): 12 ds_read_b128 -> mid barrier -> 16 MFMA (setprio-wrapped)
#define QUAD(QM, QN) do {                                                     \
    short8 af[4][2], bf[2][2];                                                \
    _Pragma("unroll") for (int mi = 0; mi < 4; ++mi)                          \
    _Pragma("unroll") for (int kk = 0; kk < 2; ++kk) {                        \
      const int row_ = wm*128 + (QM)*64 + mi*16 + l15;                        \
      const int ch_ = ((kk*4 + lh) ^ (row_ & 7));                             \
      af[mi][kk] = *(const short8*)(ldsAb + row_*64 + ch_*8);                 \
    }                                                                         \
    _Pragma("unroll") for (int ni = 0; ni < 2; ++ni)                          \
    _Pragma("unroll") for (int kk = 0; kk < 2; ++kk) {                        \
      const int row_ = wn*64 + (QN)*32 + ni*16 + l15;                         \
      const int ch_ = ((kk*4 + lh) ^ (row_ & 7));                             \
      bf[ni][kk] = *(const short8*)(ldsBb + row_*64 + ch_*8);                 \
    }                                                                         \
    asm volatile("s_barrier" ::: "memory");                                   \
    __builtin_amdgcn_s_setprio(1);                                            \
    _Pragma("unroll") for (int kk = 0; kk < 2; ++kk)                          \
    _Pragma("unroll") for (int mi = 0; mi < 4; ++mi)                          \
    _Pragma("unroll") for (int ni = 0; ni < 2; ++ni)                          \
      acc[(QM)*4 + mi][(QN)*2 + ni] = __builtin_amdgcn_mfma_f32_16x16x32_f16( \
          __builtin_bit_cast(f16x8, bf[ni][kk]),                              \
          __builtin_bit_cast(f16x8, af[mi][kk]),                              \
          acc[(QM)*4 + mi][(QN)*2 + ni], 0, 0, 0);                            \
    __builtin_amdgcn_s_setprio(0);                                            \
} while (0)

#define PH_END(N_) do { asm volatile("s_waitcnt vmcnt(" #N_ ")" ::: "memory"); \
                        asm volatile("s_barrier" ::: "memory"); } while (0)

template<int MODE>
__global__ __launch_bounds__(512, 1) void gemm256_kernel(
    const unsigned short* __restrict__ Abase,
    const unsigned short* __restrict__ Bbase,
    unsigned short* __restrict__ Oh,
    float* __restrict__ Of,
    const float* __restrict__ bias,
    const int* __restrict__ rows,
    const float* __restrict__ roww,
    const int* __restrict__ off,
    const int K, const int N, const int Astride, const int c0, const int lgGX)
{
  // XCD-chunked bijective block remap (m204)
  const unsigned orig = blockIdx.x, nwg = gridDim.x;
  const unsigned q8 = nwg >> 3, r8 = nwg & 7;
  const unsigned xcd = orig & 7, pos = orig >> 3;
  const unsigned wrk = (xcd < r8 ? xcd * (q8 + 1) : r8 * (q8 + 1) + (xcd - r8) * q8) + pos;
  const int tn = (int)(wrk & ((1u << lgGX) - 1u));
  const int rowbase = c0 + (int)(wrk >> lgGX) * 256;

  const int off8 = off[NEXP];
  if (rowbase >= off8) return;
  int e = 0;
  while (e < NEXP - 1 && rowbase >= off[e + 1]) ++e;

  // LDS: A[2 buf][256][64] fp16 @0, B[2 buf][256][64] fp16 @32768 shorts = 128 KiB
  __shared__ __align__(16) unsigned short lds[65536];

  const int tid = threadIdx.x, lane = tid & 63, wid = tid >> 6;
  const int wm = wid >> 2, wn = wid & 3;       // 2 x 4 waves, each owns 128x64
  const int l15 = lane & 15, lh = lane >> 4;
  const int kc8 = ((tid & 7) ^ ((tid >> 3) & 7)) * 8;   // pre-swizzled source chunk

  f32x4 acc[8][4] = {};

  // per-thread staging offsets (element units)
  size_t aoff[2][2];
#pragma unroll
  for (int qm = 0; qm < 2; ++qm)
#pragma unroll
    for (int i = 0; i < 2; ++i) {
      int grow = rowbase + i * 128 + qm * 64 + (tid >> 3);
      size_t arow = (MODE == 0) ? (size_t)rows[grow] : (size_t)(grow - c0);
      aoff[qm][i] = arow * (size_t)Astride;
    }
  size_t boff[2][2];
#pragma unroll
  for (int qn = 0; qn < 2; ++qn)
#pragma unroll
    for (int i = 0; i < 2; ++i) {
      int rl = i * 64 + (tid >> 3);
      int brow = (rl >> 5) * 64 + qn * 32 + (rl & 31);
      boff[qn][i] = ((size_t)e * N + (size_t)(tn * 256 + brow)) * (size_t)K;
    }
  int bdst[2];
#pragma unroll
  for (int i = 0; i < 2; ++i)
    bdst[i] = (i * 2 + (tid >> 8)) * 4096 + (tid & 255) * 8;

  const int nt = K >> 6;
  // prologue: issue stream [t0.Bq0, t0.Aq0, t0.Bq1, t0.Aq1, t1.Bq0, t1.Aq0]
  STAGE_B(0, 0, 0); STAGE_A(0, 0, 0); STAGE_B(0, 1, 0); STAGE_A(0, 1, 0);
  STAGE_B(1, 0, 1); STAGE_A(1, 0, 1);
  PH_END(8);   // t0.Bq0/Aq0 done (8 newer loads outstanding)

  for (int t = 0; t < nt; ++t) {
    const int b = t & 1;
    const bool tw = (t + 2 >= nt);               // tail: drain instead of counted
    const unsigned short* ldsAb = lds + b * 16384;
    const unsigned short* ldsBb = lds + 32768 + b * 16384;
    // ph0: quadrant (0,0); stage (t+1).Bq1 -> buf b^1
    if (t + 1 < nt) STAGE_B(b ^ 1, 1, t + 1);
    QUAD(0, 0);
    if (tw) PH_END(0); else PH_END(6);           // guards ph1's need: t.Aq1
    // ph1: (1,0); stage (t+1).Aq1 -> buf b^1
    if (t + 1 < nt) STAGE_A(b ^ 1, 1, t + 1);
    QUAD(1, 0);
    if (tw) PH_END(0); else PH_END(10);          // guards ph2's need: t.Bq1
    // ph2: (0,1); stage (t+2).Bq0 -> buf b (t's Bq0 dead after ph1)
    if (t + 2 < nt) STAGE_B(b, 0, t + 2);
    QUAD(0, 1);
    asm volatile("s_barrier" ::: "memory");      // ph3 needs nothing new
    // ph3: (1,1); stage (t+2).Aq0 -> buf b (t's Aq0 dead after ph2)
    if (t + 2 < nt) STAGE_A(b, 0, t + 2);
    QUAD(1, 1);
    if (tw) PH_END(0); else PH_END(8);           // guards (t+1).ph0: (t+1).Aq0/Bq0
  }

  if (MODE == 2) {
    // fallback: scattered f32 atomics into d_out
#pragma unroll
    for (int mi = 0; mi < 8; ++mi) {
      int g = rowbase + wm * 128 + mi * 16 + l15;
      int token = rows[g];
      float wgt = roww[g];
#pragma unroll
      for (int ni = 0; ni < 4; ++ni) {
        int n = tn * 256 + wn * 64 + ni * 16 + lh * 4;
        f32x4 v = acc[mi][ni];
        f32x4 bv = *(const f32x4*)(bias + (size_t)e * N + n);
#pragma unroll
        for (int qd = 0; qd < 4; ++qd)
          atomicAdd(&Of[(size_t)token * N + n + qd], wgt * (v[qd] + bv[qd]));
      }
    }
    return;
  }

  // epilogue: acc -> swizzled fp16 tile in LDS (reuse staging LDS) -> coalesced stores
  __syncthreads();
#pragma unroll
  for (int mi = 0; mi < 8; ++mi) {
    const int row = wm * 128 + mi * 16 + l15;
    float wgt = 1.0f;
    if (MODE == 3) wgt = roww[rowbase + row];
#pragma unroll
    for (int ni = 0; ni < 4; ++ni) {
      const int col = wn * 64 + ni * 16 + lh * 4;
      f32x4 v = acc[mi][ni];
      f32x4 bv = *(const f32x4*)(bias + (size_t)e * N + tn * 256 + col);
      u16x4 h;
#pragma unroll
      for (int qd = 0; qd < 4; ++qd) {
        float vv = v[qd] + bv[qd];
        if (MODE == 3) vv *= wgt;
        h[qd] = f2h(vv);
      }
      const int ch = (col >> 3) ^ (row & 7);
      *(u16x4*)(lds + row * 256 + ch * 8 + (col & 7)) = h;
    }
  }
  __syncthreads();
#pragma unroll
  for (int it = 0; it < 16; ++it) {
    const int flat = it * 512 + tid;
    const int row = flat >> 5;              // 0..255
    const int ch = flat & 31;               // 32 x 16B = full 512B row
    const int chs = ch ^ (row & 7);
    short8 v = *(const short8*)(lds + row * 256 + chs * 8);
    const int g = rowbase + row;
    unsigned short* dst = (MODE == 3) ? (Oh + (size_t)g * N)
                                      : (Oh + (size_t)(g - c0) * N);
    *(short8*)(dst + tn * 256 + ch * 8) = v;
  }
}

// ---------------- LayerNorm + exact GELU: fp16 in, fp16 out (f32 stats) ------
__global__ __launch_bounds__(256) void ln_gelu_kernel(
    const unsigned short* __restrict__ src, unsigned short* __restrict__ dst,
    const float* __restrict__ gam, const float* __restrict__ bet,
    const int* __restrict__ off, const int c0)
{
  const int g = c0 + blockIdx.x;
  if (g >= off[NEXP]) return;
  int e = 0;
#pragma unroll
  for (int q = 1; q < NEXP; ++q) if (g >= off[q]) e = q;
  const int tid = threadIdx.x;
  const unsigned short* s0 = src + (size_t)(g - c0) * HID;
  short8 hv = *(const short8*)(s0 + tid * 8);
  float v[8];
  float s = 0.f, sq = 0.f;
#pragma unroll
  for (int q = 0; q < 8; ++q) {
    v[q] = h2f((unsigned short)hv[q]);
    s += v[q]; sq += v[q] * v[q];
  }
#pragma unroll
  for (int sh = 32; sh > 0; sh >>= 1) { s += __shfl_xor(s, sh); sq += __shfl_xor(sq, sh); }
  __shared__ float rs_[4], rq_[4];
  const int lane = tid & 63, wid = tid >> 6;
  if (lane == 0) { rs_[wid] = s; rq_[wid] = sq; }
  __syncthreads();
  s  = rs_[0] + rs_[1] + rs_[2] + rs_[3];
  sq = rq_[0] + rq_[1] + rq_[2] + rq_[3];
  const float mu  = s * (1.0f / HID);
  const float var = sq * (1.0f / HID) - mu * mu;
  const float rstd = rsqrtf(var + 1e-5f);
  const float* gp = gam + (size_t)e * HID + tid * 8;
  const float* bp = bet + (size_t)e * HID + tid * 8;
  short8 o;
#pragma unroll
  for (int q = 0; q < 8; ++q) {
    float t = (v[q] - mu) * rstd * gp[q] + bp[q];
    o[q] = (short)f2h(gelu_exact(t));
  }
  *(short8*)(dst + (size_t)(g - c0) * HID + tid * 8) = o;
}

// ---------------- deterministic 2-row combine (fp16 Y -> f32 out) ------------
__global__ __launch_bounds__(256) void combine_kernel(
    const unsigned short* __restrict__ Y, const int* __restrict__ pair,
    float* __restrict__ out)
{
  const int n = blockIdx.x;
  const int j = threadIdx.x * 4;
  const int r1 = pair[2 * n], r2 = pair[2 * n + 1];
  u16x4 a = *(const u16x4*)(Y + (size_t)r1 * OUTD + j);
  u16x4 b = *(const u16x4*)(Y + (size_t)r2 * OUTD + j);
  f32x4 o;
#pragma unroll
  for (int qd = 0; qd < 4; ++qd) o[qd] = h2f(a[qd]) + h2f(b[qd]);
  *(f32x4*)(out + (size_t)n * OUTD + j) = o;
}

// fallback diagnostic: encode ws_size (MB) into out[0]
__global__ void probe_kernel(float* out, float v) {
  if (threadIdx.x == 0 && blockIdx.x == 0) out[0] = v;
}

extern "C" void kernel_launch(void* const* d_in, const int* in_sizes, int n_in,
                              void* d_out, int out_size, void* d_ws, size_t ws_size,
                              hipStream_t stream) {
  (void)in_sizes; (void)n_in;
  const float* x   = (const float*)d_in[0];
  const float* Wg1 = (const float*)d_in[1];
  const float* Wg2 = (const float*)d_in[2];
  const float* W1  = (const float*)d_in[3];
  const float* b1  = (const float*)d_in[4];
  const float* g1  = (const float*)d_in[5];
  const float* be1 = (const float*)d_in[6];
  const float* W2  = (const float*)d_in[7];
  const float* b2  = (const float*)d_in[8];
  const float* g2  = (const float*)d_in[9];
  const float* be2 = (const float*)d_in[10];
  const float* W3  = (const float*)d_in[11];
  const float* b3  = (const float*)d_in[12];
  float* out = (float*)d_out;

  uint8_t* w = (uint8_t*)d_ws;
  auto alloc = [&](size_t bytes) {
    uint8_t* p = w;
    w += (bytes + 255) & ~(size_t)255;
    return p;
  };
  unsigned short* xh   = (unsigned short*)alloc((size_t)N_TOK * DIM * 2);
  unsigned short* Wt1  = (unsigned short*)alloc((size_t)NEXP * DIM * HID * 2);
  unsigned short* Wt2  = (unsigned short*)alloc((size_t)NEXP * HID * HID * 2);
  unsigned short* Wt3  = (unsigned short*)alloc((size_t)NEXP * HID * OUTD * 2);
  int*   rows  = (int*)alloc((size_t)PADTOT * 4);
  float* roww  = (float*)alloc((size_t)PADTOT * 4);
  int*   tok_e = (int*)alloc((size_t)2 * N_TOK * 4);
  float* tok_w = (float*)alloc((size_t)2 * N_TOK * 4);
  int*   pair  = (int*)alloc((size_t)2 * N_TOK * 4);
  int*   cnt   = (int*)alloc(256);
  int*   off   = (int*)alloc(256);
  int*   cur   = (int*)alloc(256);
  size_t fixed_used = (size_t)(w - (uint8_t*)d_ws);

  // adaptive chunk rows: act1h (fp16) + act2 (fp16) = 8192 B/row, 256-row granules
  long long availLL = (long long)ws_size - (long long)fixed_used - 4096;
  int R = 0;
  if (availLL > 0) {
    long long r = availLL / (HID * 2 + HID * 2);
    if (r > PADTOT) r = PADTOT;
    R = (int)(r & ~255LL);
  }
  if (R < 256) {   // diagnostic fallback: out[0] = ws_size in MB
    hipMemsetAsync(d_out, 0, (size_t)out_size * sizeof(float), stream);
    probe_kernel<<<1, 64, 0, stream>>>(out, (float)(ws_size >> 20));
    return;
  }
  unsigned short* act1h = (unsigned short*)alloc((size_t)R * HID * 2);
  unsigned short* act2  = (unsigned short*)alloc((size_t)R * HID * 2);
  const bool single = (R >= PADTOT);   // Y (fp16 [PADTOT][1024]) aliases act1h
  unsigned short* Yh = act1h;

  hipMemsetAsync(cnt, 0, NEXP * sizeof(int), stream);
  hipMemsetAsync(rows, 0, (size_t)PADTOT * 4, stream);   // dummy rows -> token 0
  hipMemsetAsync(roww, 0, (size_t)PADTOT * 4, stream);   // dummy weight -> 0.0
  if (!single)
    hipMemsetAsync(d_out, 0, (size_t)out_size * sizeof(float), stream);  // atomic target

  gate_kernel<<<N_TOK / 8, 256, 0, stream>>>(x, Wg1, Wg2, tok_e, tok_w, cnt);
  offsets_kernel<<<1, 64, 0, stream>>>(cnt, off, cur);
  scatter_kernel<<<N_TOK / 256, 256, 0, stream>>>(tok_e, tok_w, cur, rows, roww, pair);

  convert_x_kernel<<<(N_TOK * DIM / 8) / 256, 256, 0, stream>>>(x, xh);
  wconv_kernel<<<dim3(HID / 32, DIM / 32, NEXP), 256, 0, stream>>>(W1, Wt1, DIM, HID);
  wconv_kernel<<<dim3(HID / 32, HID / 32, NEXP), 256, 0, stream>>>(W2, Wt2, HID, HID);
  wconv_kernel<<<dim3(OUTD / 32, HID / 32, NEXP), 256, 0, stream>>>(W3, Wt3, HID, OUTD);

  for (int c0 = 0; c0 < PADTOT; c0 += R) {
    int Rc = PADTOT - c0; if (Rc > R) Rc = R;
    const int yt = Rc / 256;
    gemm256_kernel<0><<<8 * yt, 512, 0, stream>>>(xh, Wt1, act1h, nullptr, b1,
                                                  rows, roww, off, DIM, HID, DIM, c0, 3);
    ln_gelu_kernel<<<Rc, 256, 0, stream>>>(act1h, act2, g1, be1, off, c0);
    gemm256_kernel<1><<<8 * yt, 512, 0, stream>>>(act2, Wt2, act1h, nullptr, b2,
                                                  rows, roww, off, HID, HID, HID, c0, 3);
    ln_gelu_kernel<<<Rc, 256, 0, stream>>>(act1h, act2, g2, be2, off, c0);
    if (single)
      gemm256_kernel<3><<<4 * yt, 512, 0, stream>>>(act2, Wt3, Yh, nullptr, b3,
                                                    rows, roww, off, HID, OUTD, HID, c0, 2);
    else
      gemm256_kernel<2><<<4 * yt, 512, 0, stream>>>(act2, Wt3, nullptr, out, b3,
                                                    rows, roww, off, HID, OUTD, HID, c0, 2);
  }
  if (single)
    combine_kernel<<<N_TOK, 256, 0, stream>>>(Yh, pair, out);
}

// Round 7
// 1564.894 us; speedup vs baseline: 1.7668x; 1.2165x over previous
//
#include <hip/hip_runtime.h>
#include <math.h>
#include <stdint.h>

#define N_TOK 16384
#define DIM   1024
#define NEXP  8
#define HID   2048
#define OUTD  1024
#define PADTOT 34816   // 2*N_TOK + 8*256 : padded compacted-row upper bound (136 tiles of 256)

typedef __attribute__((ext_vector_type(8))) short short8;
typedef __attribute__((ext_vector_type(8))) _Float16 f16x8;
typedef __attribute__((ext_vector_type(4))) float f32x4;
typedef __attribute__((ext_vector_type(4))) unsigned short u16x4;

__device__ __forceinline__ unsigned short f2h(float f) {
  return __builtin_bit_cast(unsigned short, (_Float16)f);   // RNE
}
__device__ __forceinline__ float h2f(unsigned short h) {
  return (float)__builtin_bit_cast(_Float16, h);
}
__device__ __forceinline__ float gelu_exact(float a) {
  return 0.5f * a * (1.0f + erff(a * 0.70710678118654752f));
}

// ---------------- gate: fp64 math, high-TLP, NO global atomics ----------------
// 2048 blocks x 256 thr; 8 tokens/block; Wg1 rows register-cached across tokens.
__global__ __launch_bounds__(256) void gate_kernel(
    const float* __restrict__ x, const float* __restrict__ Wg1,
    const float* __restrict__ Wg2,
    int* __restrict__ tok_e, float* __restrict__ tok_w)
{
  const int tid = threadIdx.x;
  const int lane = tid & 63, wid = tid >> 6;
  const f32x4* __restrict__ Wg1v = (const f32x4*)Wg1;   // [1024][4xf32x4]
  // register-cache my 4 rows of Wg1 (d = tid + 256*i), 16 f32 each -> 16 VGPR
  f32x4 wreg[4][4];
#pragma unroll
  for (int i = 0; i < 4; ++i)
#pragma unroll
    for (int c = 0; c < 4; ++c)
      wreg[i][c] = Wg1v[(size_t)(tid + 256 * i) * 4 + c];

  __shared__ double red[4 * 16];

  for (int tk = 0; tk < 8; ++tk) {
    const int n = blockIdx.x * 8 + tk;
    // coalesced x loads: thread covers d = tid + 256*i
    double xv[4];
#pragma unroll
    for (int i = 0; i < 4; ++i)
      xv[i] = (double)x[(size_t)n * DIM + tid + 256 * i];
    double acc[16];
#pragma unroll
    for (int j = 0; j < 16; ++j) acc[j] = 0.0;
#pragma unroll
    for (int i = 0; i < 4; ++i)
#pragma unroll
      for (int c = 0; c < 4; ++c)
#pragma unroll
        for (int q = 0; q < 4; ++q)
          acc[c * 4 + q] += xv[i] * (double)wreg[i][c][q];
    // wave reduction of 16 accumulators
#pragma unroll
    for (int j = 0; j < 16; ++j)
#pragma unroll
      for (int s = 32; s > 0; s >>= 1) acc[j] += __shfl_xor(acc[j], s);
    if (lane == 0) {
#pragma unroll
      for (int j = 0; j < 16; ++j) red[wid * 16 + j] = acc[j];
    }
    __syncthreads();
    if (wid == 0) {
      // lane j (<16) finalizes logit j; others idle-safe
      double t = 0.0;
      if (lane < 16) {
        t = red[lane] + red[16 + lane] + red[32 + lane] + red[48 + lane];
        t = tanh(t);
      }
      const int e = lane & 7;
      double ge = 0.0;
#pragma unroll
      for (int j = 0; j < 16; ++j) {
        double tj = __shfl(t, j);
        ge += tj * (double)Wg2[j * 8 + e];
      }
      // softmax over 8 within each 8-lane group
      double m = ge;
#pragma unroll
      for (int s = 1; s < 8; s <<= 1) m = fmax(m, __shfl_xor(m, s));
      double p = exp(ge - m);
      double ssum = p;
#pragma unroll
      for (int s = 1; s < 8; s <<= 1) ssum += __shfl_xor(ssum, s);
      double wsm = p / ssum;
      // top-2 via 64-bit keys (ties -> lowest index, like lax.top_k)
      unsigned long long key =
          (((unsigned long long)__double_as_longlong(wsm)) & ~7ULL) |
          (unsigned long long)(7 - e);
      unsigned long long k1 = key;
#pragma unroll
      for (int s = 1; s < 8; s <<= 1) { unsigned long long o = __shfl_xor(k1, s); k1 = (o > k1) ? o : k1; }
      int e1 = 7 - (int)(k1 & 7ULL);
      unsigned long long k2 = (e == e1) ? 0ULL : key;
#pragma unroll
      for (int s = 1; s < 8; s <<= 1) { unsigned long long o = __shfl_xor(k2, s); k2 = (o > k2) ? o : k2; }
      int e2 = 7 - (int)(k2 & 7ULL);
      double w1v = __longlong_as_double((long long)(k1 & ~7ULL));
      double w2v = __longlong_as_double((long long)(k2 & ~7ULL));
      double inv = 1.0 / (w1v + w2v + 1e-12);
      if (lane == 0) {
        tok_e[2 * n] = e1; tok_e[2 * n + 1] = e2;
        tok_w[2 * n] = (float)(w1v * inv); tok_w[2 * n + 1] = (float)(w2v * inv);
      }
    }
    __syncthreads();
  }
}

// ---------------- hist: LDS histogram, 8 global atomics per block ------------
__global__ __launch_bounds__(256) void hist_kernel(
    const int* __restrict__ tok_e, int* __restrict__ cnt)
{
  __shared__ int h[NEXP];
  const int tid = threadIdx.x;
  if (tid < NEXP) h[tid] = 0;
  __syncthreads();
  const int base = blockIdx.x * 512;
  atomicAdd(&h[tok_e[base + tid]], 1);
  atomicAdd(&h[tok_e[base + 256 + tid]], 1);
  __syncthreads();
  if (tid < NEXP) atomicAdd(&cnt[tid], h[tid]);
}

// offsets padded to multiples of 256 so every 256-row tile is single-expert
__global__ void offsets_kernel(const int* __restrict__ cnt, int* __restrict__ off,
                               int* __restrict__ cur) {
  if (threadIdx.x == 0) {
    int a = 0;
    for (int e = 0; e < NEXP; ++e) {
      off[e] = a; cur[e] = a;
      a += (cnt[e] + 255) & ~255;
    }
    off[NEXP] = a;
  }
}

// ---------------- scatter: per-block LDS rank + one base-claim per expert ----
// Slot order within an expert is nondeterministic, but numerically inert:
// each routed row depends only on (token, expert); combine gathers via pair[].
__global__ __launch_bounds__(256) void scatter_kernel(
    const int* __restrict__ tok_e, const float* __restrict__ tok_w,
    int* __restrict__ cur, int* __restrict__ rows, float* __restrict__ roww,
    int* __restrict__ pair)
{
  __shared__ int lcnt[NEXP];
  __shared__ int lbase[NEXP];
  const int tid = threadIdx.x;
  if (tid < NEXP) lcnt[tid] = 0;
  __syncthreads();
  const int n = blockIdx.x * 256 + tid;
  const int e0 = tok_e[2 * n], e1 = tok_e[2 * n + 1];
  const int r0 = atomicAdd(&lcnt[e0], 1);
  const int r1 = atomicAdd(&lcnt[e1], 1);
  __syncthreads();
  if (tid < NEXP) lbase[tid] = atomicAdd(&cur[tid], lcnt[tid]);
  __syncthreads();
  const int p0 = lbase[e0] + r0;
  const int p1 = lbase[e1] + r1;
  rows[p0] = n; roww[p0] = tok_w[2 * n];     pair[2 * n]     = p0;
  rows[p1] = n; roww[p1] = tok_w[2 * n + 1]; pair[2 * n + 1] = p1;
}

// ---------------- fp32 -> fp16 converts ----------------
__global__ __launch_bounds__(256) void convert_x_kernel(
    const float* __restrict__ x, unsigned short* __restrict__ xh)
{
  size_t i = ((size_t)blockIdx.x * 256 + threadIdx.x) * 8;
  f32x4 a = *(const f32x4*)(x + i);
  f32x4 b = *(const f32x4*)(x + i + 4);
  short8 o;
#pragma unroll
  for (int q = 0; q < 4; ++q) { o[q] = (short)f2h(a[q]); o[q + 4] = (short)f2h(b[q]); }
  *(short8*)(xh + i) = o;
}

// transpose+convert: W[e][K][N] fp32 -> Wt[e][N][K] fp16
__global__ __launch_bounds__(256) void wconv_kernel(
    const float* __restrict__ W, unsigned short* __restrict__ Wt,
    const int K, const int N)
{
  __shared__ float t[32][33];
  const int e = blockIdx.z;
  const float* We = W + (size_t)e * K * N;
  unsigned short* Wte = Wt + (size_t)e * K * N;
  const int n0 = blockIdx.x * 32, k0 = blockIdx.y * 32;
  const int tid = threadIdx.x;
  const int r = tid >> 3, c4 = (tid & 7) * 4;
  f32x4 v = *(const f32x4*)(We + (size_t)(k0 + r) * N + n0 + c4);
  t[r][c4 + 0] = v[0]; t[r][c4 + 1] = v[1]; t[r][c4 + 2] = v[2]; t[r][c4 + 3] = v[3];
  __syncthreads();
  u16x4 o;
#pragma unroll
  for (int q = 0; q < 4; ++q) o[q] = f2h(t[c4 + q][r]);
  *(u16x4*)(Wte + (size_t)(n0 + r) * K + k0 + c4) = o;
}

// ============ 256x256 8-wave 8-phase routed GEMM (fp16 MFMA, fp32 acc) ============
// Per K-tile (BK=64) 4 quadrant-phases; staging at quarter granularity into dying
// LDS sub-slots; counted vmcnt {6,10,-,8}; raw s_barrier; setprio around MFMA.
// MODE 0: A = gathered xh rows, out = act1h (acc+bias)
// MODE 1: A = act2,             out = act1h (acc+bias)
// MODE 2: A = act2,             out = d_out atomicAdd f32 (ws-too-small fallback)
// MODE 3: A = act2,             out = Y fp16 w*(acc+bias)

#define STAGE_A(SB, QM, T) do {                                               \
  _Pragma("unroll") for (int i_ = 0; i_ < 2; ++i_)                            \
    __builtin_amdgcn_global_load_lds(                                         \
      (const __attribute__((address_space(1))) void*)(Abase + aoff[QM][i_] + (size_t)(T)*64 + kc8), \
      (__attribute__((address_space(3))) void*)(lds + (SB)*16384 + (QM)*4096 + i_*8192 + tid*8), \
      16, 0, 0);                                                              \
} while (0)

#define STAGE_B(SB, QN, T) do {                                               \
  _Pragma("unroll") for (int i_ = 0; i_ < 2; ++i_)                            \
    __builtin_amdgcn_global_load_lds(                                         \
      (const __attribute__((address_space(1))) void*)(Bbase + boff[QN][i_] + (size_t)(T)*64 + kc8), \
      (__attribute__((address_space(3))) void*)(lds + 32768 + (SB)*16384 + (QN)*2048 + bdst[i_]), \
      16, 0, 0);                                                              \
} while (0)

// quadrant (QM,QN): 12 ds_read_b128 -> mid barrier -> 16 MFMA (setprio-wrapped)
#define QUAD(QM, QN) do {                                                     \
    short8 af[4][2], bf[2][2];                                                \
    _Pragma("unroll") for (int mi = 0; mi < 4; ++mi)                          \
    _Pragma("unroll") for (int kk = 0; kk < 2; ++kk) {                        \
      const int row_ = wm*128 + (QM)*64 + mi*16 + l15;                        \
      const int ch_ = ((kk*4 + lh) ^ (row_ & 7));                             \
      af[mi][kk] = *(const short8*)(ldsAb + row_*64 + ch_*8);                 \
    }                                                                         \
    _Pragma("unroll") for (int ni = 0; ni < 2; ++ni)                          \
    _Pragma("unroll") for (int kk = 0; kk < 2; ++kk) {                        \
      const int row_ = wn*64 + (QN)*32 + ni*16 + l15;                         \
      const int ch_ = ((kk*4 + lh) ^ (row_ & 7));                             \
      bf[ni][kk] = *(const short8*)(ldsBb + row_*64 + ch_*8);                 \
    }                                                                         \
    asm volatile("s_barrier" ::: "memory");                                   \
    __builtin_amdgcn_s_setprio(1);                                            \
    _Pragma("unroll") for (int kk = 0; kk < 2; ++kk)                          \
    _Pragma("unroll") for (int mi = 0; mi < 4; ++mi)                          \
    _Pragma("unroll") for (int ni = 0; ni < 2; ++ni)                          \
      acc[(QM)*4 + mi][(QN)*2 + ni] = __builtin_amdgcn_mfma_f32_16x16x32_f16( \
          __builtin_bit_cast(f16x8, bf[ni][kk]),                              \
          __builtin_bit_cast(f16x8, af[mi][kk]),                              \
          acc[(QM)*4 + mi][(QN)*2 + ni], 0, 0, 0);                            \
    __builtin_amdgcn_s_setprio(0);                                            \
} while (0)

#define PH_END(N_) do { asm volatile("s_waitcnt vmcnt(" #N_ ")" ::: "memory"); \
                        asm volatile("s_barrier" ::: "memory"); } while (0)

template<int MODE>
__global__ __launch_bounds__(512, 1) void gemm256_kernel(
    const unsigned short* __restrict__ Abase,
    const unsigned short* __restrict__ Bbase,
    unsigned short* __restrict__ Oh,
    float* __restrict__ Of,
    const float* __restrict__ bias,
    const int* __restrict__ rows,
    const float* __restrict__ roww,
    const int* __restrict__ off,
    const int K, const int N, const int Astride, const int c0, const int lgGX)
{
  // XCD-chunked bijective block remap (m204)
  const unsigned orig = blockIdx.x, nwg = gridDim.x;
  const unsigned q8 = nwg >> 3, r8 = nwg & 7;
  const unsigned xcd = orig & 7, pos = orig >> 3;
  const unsigned wrk = (xcd < r8 ? xcd * (q8 + 1) : r8 * (q8 + 1) + (xcd - r8) * q8) + pos;
  const int tn = (int)(wrk & ((1u << lgGX) - 1u));
  const int rowbase = c0 + (int)(wrk >> lgGX) * 256;

  const int off8 = off[NEXP];
  if (rowbase >= off8) return;
  int e = 0;
  while (e < NEXP - 1 && rowbase >= off[e + 1]) ++e;

  // LDS: A[2 buf][256][64] fp16 @0, B[2 buf][256][64] fp16 @32768 shorts = 128 KiB
  __shared__ __align__(16) unsigned short lds[65536];

  const int tid = threadIdx.x, lane = tid & 63, wid = tid >> 6;
  const int wm = wid >> 2, wn = wid & 3;       // 2 x 4 waves, each owns 128x64
  const int l15 = lane & 15, lh = lane >> 4;
  const int kc8 = ((tid & 7) ^ ((tid >> 3) & 7)) * 8;   // pre-swizzled source chunk

  f32x4 acc[8][4] = {};

  // per-thread staging offsets (element units)
  size_t aoff[2][2];
#pragma unroll
  for (int qm = 0; qm < 2; ++qm)
#pragma unroll
    for (int i = 0; i < 2; ++i) {
      int grow = rowbase + i * 128 + qm * 64 + (tid >> 3);
      size_t arow = (MODE == 0) ? (size_t)rows[grow] : (size_t)(grow - c0);
      aoff[qm][i] = arow * (size_t)Astride;
    }
  size_t boff[2][2];
#pragma unroll
  for (int qn = 0; qn < 2; ++qn)
#pragma unroll
    for (int i = 0; i < 2; ++i) {
      int rl = i * 64 + (tid >> 3);
      int brow = (rl >> 5) * 64 + qn * 32 + (rl & 31);
      boff[qn][i] = ((size_t)e * N + (size_t)(tn * 256 + brow)) * (size_t)K;
    }
  int bdst[2];
#pragma unroll
  for (int i = 0; i < 2; ++i)
    bdst[i] = (i * 2 + (tid >> 8)) * 4096 + (tid & 255) * 8;

  const int nt = K >> 6;
  // prologue: issue stream [t0.Bq0, t0.Aq0, t0.Bq1, t0.Aq1, t1.Bq0, t1.Aq0]
  STAGE_B(0, 0, 0); STAGE_A(0, 0, 0); STAGE_B(0, 1, 0); STAGE_A(0, 1, 0);
  STAGE_B(1, 0, 1); STAGE_A(1, 0, 1);
  PH_END(8);   // t0.Bq0/Aq0 done (8 newer loads outstanding)

  for (int t = 0; t < nt; ++t) {
    const int b = t & 1;
    const bool tw = (t + 2 >= nt);               // tail: drain instead of counted
    const unsigned short* ldsAb = lds + b * 16384;
    const unsigned short* ldsBb = lds + 32768 + b * 16384;
    // ph0: quadrant (0,0); stage (t+1).Bq1 -> buf b^1
    if (t + 1 < nt) STAGE_B(b ^ 1, 1, t + 1);
    QUAD(0, 0);
    if (tw) PH_END(0); else PH_END(6);           // guards ph1's need: t.Aq1
    // ph1: (1,0); stage (t+1).Aq1 -> buf b^1
    if (t + 1 < nt) STAGE_A(b ^ 1, 1, t + 1);
    QUAD(1, 0);
    if (tw) PH_END(0); else PH_END(10);          // guards ph2's need: t.Bq1
    // ph2: (0,1); stage (t+2).Bq0 -> buf b (t's Bq0 dead after ph1)
    if (t + 2 < nt) STAGE_B(b, 0, t + 2);
    QUAD(0, 1);
    asm volatile("s_barrier" ::: "memory");      // ph3 needs nothing new
    // ph3: (1,1); stage (t+2).Aq0 -> buf b (t's Aq0 dead after ph2)
    if (t + 2 < nt) STAGE_A(b, 0, t + 2);
    QUAD(1, 1);
    if (tw) PH_END(0); else PH_END(8);           // guards (t+1).ph0: (t+1).Aq0/Bq0
  }

  if (MODE == 2) {
    // fallback: scattered f32 atomics into d_out
#pragma unroll
    for (int mi = 0; mi < 8; ++mi) {
      int g = rowbase + wm * 128 + mi * 16 + l15;
      int token = rows[g];
      float wgt = roww[g];
#pragma unroll
      for (int ni = 0; ni < 4; ++ni) {
        int n = tn * 256 + wn * 64 + ni * 16 + lh * 4;
        f32x4 v = acc[mi][ni];
        f32x4 bv = *(const f32x4*)(bias + (size_t)e * N + n);
#pragma unroll
        for (int qd = 0; qd < 4; ++qd)
          atomicAdd(&Of[(size_t)token * N + n + qd], wgt * (v[qd] + bv[qd]));
      }
    }
    return;
  }

  // epilogue: acc -> swizzled fp16 tile in LDS (reuse staging LDS) -> coalesced stores
  __syncthreads();
#pragma unroll
  for (int mi = 0; mi < 8; ++mi) {
    const int row = wm * 128 + mi * 16 + l15;
    float wgt = 1.0f;
    if (MODE == 3) wgt = roww[rowbase + row];
#pragma unroll
    for (int ni = 0; ni < 4; ++ni) {
      const int col = wn * 64 + ni * 16 + lh * 4;
      f32x4 v = acc[mi][ni];
      f32x4 bv = *(const f32x4*)(bias + (size_t)e * N + tn * 256 + col);
      u16x4 h;
#pragma unroll
      for (int qd = 0; qd < 4; ++qd) {
        float vv = v[qd] + bv[qd];
        if (MODE == 3) vv *= wgt;
        h[qd] = f2h(vv);
      }
      const int ch = (col >> 3) ^ (row & 7);
      *(u16x4*)(lds + row * 256 + ch * 8 + (col & 7)) = h;
    }
  }
  __syncthreads();
#pragma unroll
  for (int it = 0; it < 16; ++it) {
    const int flat = it * 512 + tid;
    const int row = flat >> 5;              // 0..255
    const int ch = flat & 31;               // 32 x 16B = full 512B row
    const int chs = ch ^ (row & 7);
    short8 v = *(const short8*)(lds + row * 256 + chs * 8);
    const int g = rowbase + row;
    unsigned short* dst = (MODE == 3) ? (Oh + (size_t)g * N)
                                      : (Oh + (size_t)(g - c0) * N);
    *(short8*)(dst + tn * 256 + ch * 8) = v;
  }
}

// ---------------- LayerNorm + exact GELU: fp16 in, fp16 out (f32 stats) ------
__global__ __launch_bounds__(256) void ln_gelu_kernel(
    const unsigned short* __restrict__ src, unsigned short* __restrict__ dst,
    const float* __restrict__ gam, const float* __restrict__ bet,
    const int* __restrict__ off, const int c0)
{
  const int g = c0 + blockIdx.x;
  if (g >= off[NEXP]) return;
  int e = 0;
#pragma unroll
  for (int q = 1; q < NEXP; ++q) if (g >= off[q]) e = q;
  const int tid = threadIdx.x;
  const unsigned short* s0 = src + (size_t)(g - c0) * HID;
  short8 hv = *(const short8*)(s0 + tid * 8);
  float v[8];
  float s = 0.f, sq = 0.f;
#pragma unroll
  for (int q = 0; q < 8; ++q) {
    v[q] = h2f((unsigned short)hv[q]);
    s += v[q]; sq += v[q] * v[q];
  }
#pragma unroll
  for (int sh = 32; sh > 0; sh >>= 1) { s += __shfl_xor(s, sh); sq += __shfl_xor(sq, sh); }
  __shared__ float rs_[4], rq_[4];
  const int lane = tid & 63, wid = tid >> 6;
  if (lane == 0) { rs_[wid] = s; rq_[wid] = sq; }
  __syncthreads();
  s  = rs_[0] + rs_[1] + rs_[2] + rs_[3];
  sq = rq_[0] + rq_[1] + rq_[2] + rq_[3];
  const float mu  = s * (1.0f / HID);
  const float var = sq * (1.0f / HID) - mu * mu;
  const float rstd = rsqrtf(var + 1e-5f);
  const float* gp = gam + (size_t)e * HID + tid * 8;
  const float* bp = bet + (size_t)e * HID + tid * 8;
  short8 o;
#pragma unroll
  for (int q = 0; q < 8; ++q) {
    float t = (v[q] - mu) * rstd * gp[q] + bp[q];
    o[q] = (short)f2h(gelu_exact(t));
  }
  *(short8*)(dst + (size_t)(g - c0) * HID + tid * 8) = o;
}

// ---------------- deterministic 2-row combine (fp16 Y -> f32 out) ------------
__global__ __launch_bounds__(256) void combine_kernel(
    const unsigned short* __restrict__ Y, const int* __restrict__ pair,
    float* __restrict__ out)
{
  const int n = blockIdx.x;
  const int j = threadIdx.x * 4;
  const int r1 = pair[2 * n], r2 = pair[2 * n + 1];
  u16x4 a = *(const u16x4*)(Y + (size_t)r1 * OUTD + j);
  u16x4 b = *(const u16x4*)(Y + (size_t)r2 * OUTD + j);
  f32x4 o;
#pragma unroll
  for (int qd = 0; qd < 4; ++qd) o[qd] = h2f(a[qd]) + h2f(b[qd]);
  *(f32x4*)(out + (size_t)n * OUTD + j) = o;
}

// fallback diagnostic: encode ws_size (MB) into out[0]
__global__ void probe_kernel(float* out, float v) {
  if (threadIdx.x == 0 && blockIdx.x == 0) out[0] = v;
}

extern "C" void kernel_launch(void* const* d_in, const int* in_sizes, int n_in,
                              void* d_out, int out_size, void* d_ws, size_t ws_size,
                              hipStream_t stream) {
  (void)in_sizes; (void)n_in;
  const float* x   = (const float*)d_in[0];
  const float* Wg1 = (const float*)d_in[1];
  const float* Wg2 = (const float*)d_in[2];
  const float* W1  = (const float*)d_in[3];
  const float* b1  = (const float*)d_in[4];
  const float* g1  = (const float*)d_in[5];
  const float* be1 = (const float*)d_in[6];
  const float* W2  = (const float*)d_in[7];
  const float* b2  = (const float*)d_in[8];
  const float* g2  = (const float*)d_in[9];
  const float* be2 = (const float*)d_in[10];
  const float* W3  = (const float*)d_in[11];
  const float* b3  = (const float*)d_in[12];
  float* out = (float*)d_out;

  uint8_t* w = (uint8_t*)d_ws;
  auto alloc = [&](size_t bytes) {
    uint8_t* p = w;
    w += (bytes + 255) & ~(size_t)255;
    return p;
  };
  unsigned short* xh   = (unsigned short*)alloc((size_t)N_TOK * DIM * 2);
  unsigned short* Wt1  = (unsigned short*)alloc((size_t)NEXP * DIM * HID * 2);
  unsigned short* Wt2  = (unsigned short*)alloc((size_t)NEXP * HID * HID * 2);
  unsigned short* Wt3  = (unsigned short*)alloc((size_t)NEXP * HID * OUTD * 2);
  int*   rows  = (int*)alloc((size_t)PADTOT * 4);
  float* roww  = (float*)alloc((size_t)PADTOT * 4);
  int*   tok_e = (int*)alloc((size_t)2 * N_TOK * 4);
  float* tok_w = (float*)alloc((size_t)2 * N_TOK * 4);
  int*   pair  = (int*)alloc((size_t)2 * N_TOK * 4);
  int*   cnt   = (int*)alloc(256);
  int*   off   = (int*)alloc(256);
  int*   cur   = (int*)alloc(256);
  size_t fixed_used = (size_t)(w - (uint8_t*)d_ws);

  // adaptive chunk rows: act1h (fp16) + act2 (fp16) = 8192 B/row, 256-row granules
  long long availLL = (long long)ws_size - (long long)fixed_used - 4096;
  int R = 0;
  if (availLL > 0) {
    long long r = availLL / (HID * 2 + HID * 2);
    if (r > PADTOT) r = PADTOT;
    R = (int)(r & ~255LL);
  }
  if (R < 256) {   // diagnostic fallback: out[0] = ws_size in MB
    hipMemsetAsync(d_out, 0, (size_t)out_size * sizeof(float), stream);
    probe_kernel<<<1, 64, 0, stream>>>(out, (float)(ws_size >> 20));
    return;
  }
  unsigned short* act1h = (unsigned short*)alloc((size_t)R * HID * 2);
  unsigned short* act2  = (unsigned short*)alloc((size_t)R * HID * 2);
  const bool single = (R >= PADTOT);   // Y (fp16 [PADTOT][1024]) aliases act1h
  unsigned short* Yh = act1h;

  hipMemsetAsync(cnt, 0, NEXP * sizeof(int), stream);
  hipMemsetAsync(rows, 0, (size_t)PADTOT * 4, stream);   // dummy rows -> token 0
  hipMemsetAsync(roww, 0, (size_t)PADTOT * 4, stream);   // dummy weight -> 0.0
  if (!single)
    hipMemsetAsync(d_out, 0, (size_t)out_size * sizeof(float), stream);  // atomic target

  gate_kernel<<<N_TOK / 8, 256, 0, stream>>>(x, Wg1, Wg2, tok_e, tok_w);
  hist_kernel<<<2 * N_TOK / 512, 256, 0, stream>>>(tok_e, cnt);
  offsets_kernel<<<1, 64, 0, stream>>>(cnt, off, cur);
  scatter_kernel<<<N_TOK / 256, 256, 0, stream>>>(tok_e, tok_w, cur, rows, roww, pair);

  convert_x_kernel<<<(N_TOK * DIM / 8) / 256, 256, 0, stream>>>(x, xh);
  wconv_kernel<<<dim3(HID / 32, DIM / 32, NEXP), 256, 0, stream>>>(W1, Wt1, DIM, HID);
  wconv_kernel<<<dim3(HID / 32, HID / 32, NEXP), 256, 0, stream>>>(W2, Wt2, HID, HID);
  wconv_kernel<<<dim3(OUTD / 32, HID / 32, NEXP), 256, 0, stream>>>(W3, Wt3, HID, OUTD);

  for (int c0 = 0; c0 < PADTOT; c0 += R) {
    int Rc = PADTOT - c0; if (Rc > R) Rc = R;
    const int yt = Rc / 256;
    gemm256_kernel<0><<<8 * yt, 512, 0, stream>>>(xh, Wt1, act1h, nullptr, b1,
                                                  rows, roww, off, DIM, HID, DIM, c0, 3);
    ln_gelu_kernel<<<Rc, 256, 0, stream>>>(act1h, act2, g1, be1, off, c0);
    gemm256_kernel<1><<<8 * yt, 512, 0, stream>>>(act2, Wt2, act1h, nullptr, b2,
                                                  rows, roww, off, HID, HID, HID, c0, 3);
    ln_gelu_kernel<<<Rc, 256, 0, stream>>>(act1h, act2, g2, be2, off, c0);
    if (single)
      gemm256_kernel<3><<<4 * yt, 512, 0, stream>>>(act2, Wt3, Yh, nullptr, b3,
                                                    rows, roww, off, HID, OUTD, HID, c0, 2);
    else
      gemm256_kernel<2><<<4 * yt, 512, 0, stream>>>(act2, Wt3, nullptr, out, b3,
                                                    rows, roww, off, HID, OUTD, HID, c0, 2);
  }
  if (single)
    combine_kernel<<<N_TOK, 256, 0, stream>>>(Yh, pair, out);
}

// Round 8
// 1443.405 us; speedup vs baseline: 1.9155x; 1.0842x over previous
//
#include <hip/hip_runtime.h>
#include <math.h>
#include <stdint.h>

#define N_TOK 16384
#define DIM   1024
#define NEXP  8
#define HID   2048
#define OUTD  1024
#define PADTOT 34816   // 2*N_TOK + 8*256 : padded compacted-row upper bound (136 tiles of 256)

typedef __attribute__((ext_vector_type(8))) short short8;
typedef __attribute__((ext_vector_type(8))) _Float16 f16x8;
typedef __attribute__((ext_vector_type(4))) float f32x4;
typedef __attribute__((ext_vector_type(4))) unsigned short u16x4;

__device__ __forceinline__ unsigned short f2h(float f) {
  return __builtin_bit_cast(unsigned short, (_Float16)f);   // RNE
}
__device__ __forceinline__ float h2f(unsigned short h) {
  return (float)__builtin_bit_cast(_Float16, h);
}
__device__ __forceinline__ float gelu_exact(float a) {
  return 0.5f * a * (1.0f + erff(a * 0.70710678118654752f));
}

// ---------------- gate: fp64 math, high-TLP, NO global atomics ----------------
__global__ __launch_bounds__(256) void gate_kernel(
    const float* __restrict__ x, const float* __restrict__ Wg1,
    const float* __restrict__ Wg2,
    int* __restrict__ tok_e, float* __restrict__ tok_w)
{
  const int tid = threadIdx.x;
  const int lane = tid & 63, wid = tid >> 6;
  const f32x4* __restrict__ Wg1v = (const f32x4*)Wg1;   // [1024][4xf32x4]
  f32x4 wreg[4][4];
#pragma unroll
  for (int i = 0; i < 4; ++i)
#pragma unroll
    for (int c = 0; c < 4; ++c)
      wreg[i][c] = Wg1v[(size_t)(tid + 256 * i) * 4 + c];

  __shared__ double red[4 * 16];

  for (int tk = 0; tk < 8; ++tk) {
    const int n = blockIdx.x * 8 + tk;
    double xv[4];
#pragma unroll
    for (int i = 0; i < 4; ++i)
      xv[i] = (double)x[(size_t)n * DIM + tid + 256 * i];
    double acc[16];
#pragma unroll
    for (int j = 0; j < 16; ++j) acc[j] = 0.0;
#pragma unroll
    for (int i = 0; i < 4; ++i)
#pragma unroll
      for (int c = 0; c < 4; ++c)
#pragma unroll
        for (int q = 0; q < 4; ++q)
          acc[c * 4 + q] += xv[i] * (double)wreg[i][c][q];
#pragma unroll
    for (int j = 0; j < 16; ++j)
#pragma unroll
      for (int s = 32; s > 0; s >>= 1) acc[j] += __shfl_xor(acc[j], s);
    if (lane == 0) {
#pragma unroll
      for (int j = 0; j < 16; ++j) red[wid * 16 + j] = acc[j];
    }
    __syncthreads();
    if (wid == 0) {
      double t = 0.0;
      if (lane < 16) {
        t = red[lane] + red[16 + lane] + red[32 + lane] + red[48 + lane];
        t = tanh(t);
      }
      const int e = lane & 7;
      double ge = 0.0;
#pragma unroll
      for (int j = 0; j < 16; ++j) {
        double tj = __shfl(t, j);
        ge += tj * (double)Wg2[j * 8 + e];
      }
      double m = ge;
#pragma unroll
      for (int s = 1; s < 8; s <<= 1) m = fmax(m, __shfl_xor(m, s));
      double p = exp(ge - m);
      double ssum = p;
#pragma unroll
      for (int s = 1; s < 8; s <<= 1) ssum += __shfl_xor(ssum, s);
      double wsm = p / ssum;
      unsigned long long key =
          (((unsigned long long)__double_as_longlong(wsm)) & ~7ULL) |
          (unsigned long long)(7 - e);
      unsigned long long k1 = key;
#pragma unroll
      for (int s = 1; s < 8; s <<= 1) { unsigned long long o = __shfl_xor(k1, s); k1 = (o > k1) ? o : k1; }
      int e1 = 7 - (int)(k1 & 7ULL);
      unsigned long long k2 = (e == e1) ? 0ULL : key;
#pragma unroll
      for (int s = 1; s < 8; s <<= 1) { unsigned long long o = __shfl_xor(k2, s); k2 = (o > k2) ? o : k2; }
      int e2 = 7 - (int)(k2 & 7ULL);
      double w1v = __longlong_as_double((long long)(k1 & ~7ULL));
      double w2v = __longlong_as_double((long long)(k2 & ~7ULL));
      double inv = 1.0 / (w1v + w2v + 1e-12);
      if (lane == 0) {
        tok_e[2 * n] = e1; tok_e[2 * n + 1] = e2;
        tok_w[2 * n] = (float)(w1v * inv); tok_w[2 * n + 1] = (float)(w2v * inv);
      }
    }
    __syncthreads();
  }
}

// ---------------- hist: LDS histogram, 8 global atomics per block ------------
__global__ __launch_bounds__(256) void hist_kernel(
    const int* __restrict__ tok_e, int* __restrict__ cnt)
{
  __shared__ int h[NEXP];
  const int tid = threadIdx.x;
  if (tid < NEXP) h[tid] = 0;
  __syncthreads();
  const int base = blockIdx.x * 512;
  atomicAdd(&h[tok_e[base + tid]], 1);
  atomicAdd(&h[tok_e[base + 256 + tid]], 1);
  __syncthreads();
  if (tid < NEXP) atomicAdd(&cnt[tid], h[tid]);
}

// offsets padded to multiples of 256 so every 256-row tile is single-expert
__global__ void offsets_kernel(const int* __restrict__ cnt, int* __restrict__ off,
                               int* __restrict__ cur) {
  if (threadIdx.x == 0) {
    int a = 0;
    for (int e = 0; e < NEXP; ++e) {
      off[e] = a; cur[e] = a;
      a += (cnt[e] + 255) & ~255;
    }
    off[NEXP] = a;
  }
}

// ---------------- scatter: per-block LDS rank + one base-claim per expert ----
__global__ __launch_bounds__(256) void scatter_kernel(
    const int* __restrict__ tok_e, const float* __restrict__ tok_w,
    int* __restrict__ cur, int* __restrict__ rows, float* __restrict__ roww,
    int* __restrict__ pair)
{
  __shared__ int lcnt[NEXP];
  __shared__ int lbase[NEXP];
  const int tid = threadIdx.x;
  if (tid < NEXP) lcnt[tid] = 0;
  __syncthreads();
  const int n = blockIdx.x * 256 + tid;
  const int e0 = tok_e[2 * n], e1 = tok_e[2 * n + 1];
  const int r0 = atomicAdd(&lcnt[e0], 1);
  const int r1 = atomicAdd(&lcnt[e1], 1);
  __syncthreads();
  if (tid < NEXP) lbase[tid] = atomicAdd(&cur[tid], lcnt[tid]);
  __syncthreads();
  const int p0 = lbase[e0] + r0;
  const int p1 = lbase[e1] + r1;
  rows[p0] = n; roww[p0] = tok_w[2 * n];     pair[2 * n]     = p0;
  rows[p1] = n; roww[p1] = tok_w[2 * n + 1]; pair[2 * n + 1] = p1;
}

// ---------------- fp32 -> fp16 converts ----------------
__global__ __launch_bounds__(256) void convert_x_kernel(
    const float* __restrict__ x, unsigned short* __restrict__ xh)
{
  size_t i = ((size_t)blockIdx.x * 256 + threadIdx.x) * 8;
  f32x4 a = *(const f32x4*)(x + i);
  f32x4 b = *(const f32x4*)(x + i + 4);
  short8 o;
#pragma unroll
  for (int q = 0; q < 4; ++q) { o[q] = (short)f2h(a[q]); o[q + 4] = (short)f2h(b[q]); }
  *(short8*)(xh + i) = o;
}

// transpose+convert: W[e][K][N] fp32 -> Wt[e][N][K] fp16
__global__ __launch_bounds__(256) void wconv_kernel(
    const float* __restrict__ W, unsigned short* __restrict__ Wt,
    const int K, const int N)
{
  __shared__ float t[32][33];
  const int e = blockIdx.z;
  const float* We = W + (size_t)e * K * N;
  unsigned short* Wte = Wt + (size_t)e * K * N;
  const int n0 = blockIdx.x * 32, k0 = blockIdx.y * 32;
  const int tid = threadIdx.x;
  const int r = tid >> 3, c4 = (tid & 7) * 4;
  f32x4 v = *(const f32x4*)(We + (size_t)(k0 + r) * N + n0 + c4);
  t[r][c4 + 0] = v[0]; t[r][c4 + 1] = v[1]; t[r][c4 + 2] = v[2]; t[r][c4 + 3] = v[3];
  __syncthreads();
  u16x4 o;
#pragma unroll
  for (int q = 0; q < 4; ++q) o[q] = f2h(t[c4 + q][r]);
  *(u16x4*)(Wte + (size_t)(n0 + r) * K + k0 + c4) = o;
}

// ============ 256x256 8-wave routed GEMM, 2-phase/K-tile, fragment-reuse ============
// P0: issue SA(t+1); read af0(8)+bf(8); bar; 32 MFMA top half; bar
// P1: issue SB(t+2); read af1(8);       bar; 32 MFMA bottom half; vmcnt(4); bar
// bf held in registers across both halves -> 24 ds_read_b128/tile (was 48).
// MODE 0: A = gathered xh rows; MODE 1: A = act2; MODE 2: atomic fallback; MODE 3: Y out.

#define STAGEA(SB_, T_) do {                                                  \
  _Pragma("unroll") for (int qm_ = 0; qm_ < 2; ++qm_)                         \
  _Pragma("unroll") for (int i_ = 0; i_ < 2; ++i_)                            \
    __builtin_amdgcn_global_load_lds(                                         \
      (const __attribute__((address_space(1))) void*)(Abase + aoff[qm_][i_] + (size_t)(T_)*64 + kc8), \
      (__attribute__((address_space(3))) void*)(lds + (SB_)*16384 + qm_*4096 + i_*8192 + tid*8), \
      16, 0, 0);                                                              \
} while (0)

#define STAGEB(SB_, T_) do {                                                  \
  _Pragma("unroll") for (int qn_ = 0; qn_ < 2; ++qn_)                         \
  _Pragma("unroll") for (int i_ = 0; i_ < 2; ++i_)                            \
    __builtin_amdgcn_global_lds_maybe(0);                                     \
} while (0)
#undef STAGEB
#define STAGEB(SB_, T_) do {                                                  \
  _Pragma("unroll") for (int qn_ = 0; qn_ < 2; ++qn_)                         \
  _Pragma("unroll") for (int i_ = 0; i_ < 2; ++i_)                            \
    __builtin_amdgcn_global_load_lds(                                         \
      (const __attribute__((address_space(1))) void*)(Bbase + boff[qn_][i_] + (size_t)(T_)*64 + kc8), \
      (__attribute__((address_space(3))) void*)(lds + 32768 + (SB_)*16384 + qn_*2048 + bdst[i_]), \
      16, 0, 0);                                                              \
} while (0)

#define LOAD_AF(QM_) do {                                                     \
    _Pragma("unroll") for (int mi = 0; mi < 4; ++mi)                          \
    _Pragma("unroll") for (int kk = 0; kk < 2; ++kk) {                        \
      const int row_ = wm*128 + (QM_)*64 + mi*16 + l15;                       \
      const int ch_ = ((kk*4 + lh) ^ (row_ & 7));                             \
      af[mi][kk] = *(const short8*)(ldsAb + row_*64 + ch_*8);                 \
    }                                                                         \
} while (0)

#define LOAD_BF() do {                                                        \
    _Pragma("unroll") for (int qn = 0; qn < 2; ++qn)                          \
    _Pragma("unroll") for (int ni = 0; ni < 2; ++ni)                          \
    _Pragma("unroll") for (int kk = 0; kk < 2; ++kk) {                        \
      const int row_ = wn*64 + qn*32 + ni*16 + l15;                           \
      const int ch_ = ((kk*4 + lh) ^ (row_ & 7));                             \
      bf[qn][ni][kk] = *(const short8*)(ldsBb + row_*64 + ch_*8);             \
    }                                                                         \
} while (0)

// 32 MFMA: half QM_ x all 4 column-fragments x K=64
#define MFMA_HALF(QM_) do {                                                   \
    __builtin_amdgcn_s_setprio(1);                                            \
    _Pragma("unroll") for (int kk = 0; kk < 2; ++kk)                          \
    _Pragma("unroll") for (int mi = 0; mi < 4; ++mi)                          \
    _Pragma("unroll") for (int qn = 0; qn < 2; ++qn)                          \
    _Pragma("unroll") for (int ni = 0; ni < 2; ++ni)                          \
      acc[(QM_)*4 + mi][qn*2 + ni] = __builtin_amdgcn_mfma_f32_16x16x32_f16(  \
          __builtin_bit_cast(f16x8, bf[qn][ni][kk]),                          \
          __builtin_bit_cast(f16x8, af[mi][kk]),                              \
          acc[(QM_)*4 + mi][qn*2 + ni], 0, 0, 0);                             \
    __builtin_amdgcn_s_setprio(0);                                            \
} while (0)

#define BARRIER() asm volatile("s_barrier" ::: "memory")
#define PH_END(N_) do { asm volatile("s_waitcnt vmcnt(" #N_ ")" ::: "memory"); \
                        asm volatile("s_barrier" ::: "memory"); } while (0)

template<int MODE>
__global__ __launch_bounds__(512, 1) void gemm256_kernel(
    const unsigned short* __restrict__ Abase,
    const unsigned short* __restrict__ Bbase,
    unsigned short* __restrict__ Oh,
    float* __restrict__ Of,
    const float* __restrict__ bias,
    const int* __restrict__ rows,
    const float* __restrict__ roww,
    const int* __restrict__ off,
    const int K, const int N, const int Astride, const int c0, const int lgGX)
{
  // XCD-chunked bijective block remap (m204)
  const unsigned orig = blockIdx.x, nwg = gridDim.x;
  const unsigned q8 = nwg >> 3, r8 = nwg & 7;
  const unsigned xcd = orig & 7, pos = orig >> 3;
  const unsigned wrk = (xcd < r8 ? xcd * (q8 + 1) : r8 * (q8 + 1) + (xcd - r8) * q8) + pos;
  const int tn = (int)(wrk & ((1u << lgGX) - 1u));
  const int rowbase = c0 + (int)(wrk >> lgGX) * 256;

  const int off8 = off[NEXP];
  if (rowbase >= off8) return;
  int e = 0;
  while (e < NEXP - 1 && rowbase >= off[e + 1]) ++e;

  // LDS: A[2 buf][256][64] fp16 @0, B[2 buf][256][64] fp16 @32768 shorts = 128 KiB
  __shared__ __align__(16) unsigned short lds[65536];

  const int tid = threadIdx.x, lane = tid & 63, wid = tid >> 6;
  const int wm = wid >> 2, wn = wid & 3;       // 2 x 4 waves, each owns 128x64
  const int l15 = lane & 15, lh = lane >> 4;
  const int kc8 = ((tid & 7) ^ ((tid >> 3) & 7)) * 8;   // pre-swizzled source chunk

  f32x4 acc[8][4] = {};

  // per-thread staging offsets (element units)
  size_t aoff[2][2];
#pragma unroll
  for (int qm = 0; qm < 2; ++qm)
#pragma unroll
    for (int i = 0; i < 2; ++i) {
      int grow = rowbase + i * 128 + qm * 64 + (tid >> 3);
      size_t arow = (MODE == 0) ? (size_t)rows[grow] : (size_t)(grow - c0);
      aoff[qm][i] = arow * (size_t)Astride;
    }
  size_t boff[2][2];
#pragma unroll
  for (int qn = 0; qn < 2; ++qn)
#pragma unroll
    for (int i = 0; i < 2; ++i) {
      int rl = i * 64 + (tid >> 3);
      int brow = (rl >> 5) * 64 + qn * 32 + (rl & 31);
      boff[qn][i] = ((size_t)e * N + (size_t)(tn * 256 + brow)) * (size_t)K;
    }
  int bdst[2];
#pragma unroll
  for (int i = 0; i < 2; ++i)
    bdst[i] = (i * 2 + (tid >> 8)) * 4096 + (tid & 255) * 8;

  const int nt = K >> 6;
  // prologue: SA(0), SB(0) into buf0; SB(1) into buf1.  vmcnt(4): t0 A+B done.
  STAGEA(0, 0); STAGEB(0, 0); STAGEB(1, 1);
  PH_END(4);

  for (int t = 0; t < nt; ++t) {
    const int b = t & 1;
    const unsigned short* ldsAb = lds + b * 16384;
    const unsigned short* ldsBb = lds + 32768 + b * 16384;
    short8 af[4][2], bf[2][2][2];
    // P0: stage next A; read af0 + all bf; compute top half
    if (t + 1 < nt) STAGEA(b ^ 1, t + 1);
    LOAD_AF(0); LOAD_BF();
    BARRIER();
    MFMA_HALF(0);
    BARRIER();
    // P1: stage t+2's B into dying B[b]; read af1; compute bottom half
    if (t + 2 < nt) STAGEB(b, t + 2);
    LOAD_AF(1);
    BARRIER();
    MFMA_HALF(1);
    if (t + 2 < nt) PH_END(4); else PH_END(0);   // guard next P0: SA(t+1) done
  }

  if (MODE == 2) {
    // fallback: scattered f32 atomics into d_out
#pragma unroll
    for (int mi = 0; mi < 8; ++mi) {
      int g = rowbase + wm * 128 + mi * 16 + l15;
      int token = rows[g];
      float wgt = roww[g];
#pragma unroll
      for (int ni = 0; ni < 4; ++ni) {
        int n = tn * 256 + wn * 64 + ni * 16 + lh * 4;
        f32x4 v = acc[mi][ni];
        f32x4 bv = *(const f32x4*)(bias + (size_t)e * N + n);
#pragma unroll
        for (int qd = 0; qd < 4; ++qd)
          atomicAdd(&Of[(size_t)token * N + n + qd], wgt * (v[qd] + bv[qd]));
      }
    }
    return;
  }

  // epilogue: acc -> swizzled fp16 tile in LDS (reuse staging LDS) -> coalesced stores
  __syncthreads();
#pragma unroll
  for (int mi = 0; mi < 8; ++mi) {
    const int row = wm * 128 + mi * 16 + l15;
    float wgt = 1.0f;
    if (MODE == 3) wgt = roww[rowbase + row];
#pragma unroll
    for (int ni = 0; ni < 4; ++ni) {
      const int col = wn * 64 + ni * 16 + lh * 4;
      f32x4 v = acc[mi][ni];
      f32x4 bv = *(const f32x4*)(bias + (size_t)e * N + tn * 256 + col);
      u16x4 h;
#pragma unroll
      for (int qd = 0; qd < 4; ++qd) {
        float vv = v[qd] + bv[qd];
        if (MODE == 3) vv *= wgt;
        h[qd] = f2h(vv);
      }
      const int ch = (col >> 3) ^ (row & 7);
      *(u16x4*)(lds + row * 256 + ch * 8 + (col & 7)) = h;
    }
  }
  __syncthreads();
#pragma unroll
  for (int it = 0; it < 16; ++it) {
    const int flat = it * 512 + tid;
    const int row = flat >> 5;              // 0..255
    const int ch = flat & 31;               // 32 x 16B = full 512B row
    const int chs = ch ^ (row & 7);
    short8 v = *(const short8*)(lds + row * 256 + chs * 8);
    const int g = rowbase + row;
    unsigned short* dst = (MODE == 3) ? (Oh + (size_t)g * N)
                                      : (Oh + (size_t)(g - c0) * N);
    *(short8*)(dst + tn * 256 + ch * 8) = v;
  }
}

// ---------------- LayerNorm + exact GELU: fp16 in, fp16 out (f32 stats) ------
__global__ __launch_bounds__(256) void ln_gelu_kernel(
    const unsigned short* __restrict__ src, unsigned short* __restrict__ dst,
    const float* __restrict__ gam, const float* __restrict__ bet,
    const int* __restrict__ off, const int c0)
{
  const int g = c0 + blockIdx.x;
  if (g >= off[NEXP]) return;
  int e = 0;
#pragma unroll
  for (int q = 1; q < NEXP; ++q) if (g >= off[q]) e = q;
  const int tid = threadIdx.x;
  const unsigned short* s0 = src + (size_t)(g - c0) * HID;
  short8 hv = *(const short8*)(s0 + tid * 8);
  float v[8];
  float s = 0.f, sq = 0.f;
#pragma unroll
  for (int q = 0; q < 8; ++q) {
    v[q] = h2f((unsigned short)hv[q]);
    s += v[q]; sq += v[q] * v[q];
  }
#pragma unroll
  for (int sh = 32; sh > 0; sh >>= 1) { s += __shfl_xor(s, sh); sq += __shfl_xor(sq, sh); }
  __shared__ float rs_[4], rq_[4];
  const int lane = tid & 63, wid = tid >> 6;
  if (lane == 0) { rs_[wid] = s; rq_[wid] = sq; }
  __syncthreads();
  s  = rs_[0] + rs_[1] + rs_[2] + rs_[3];
  sq = rq_[0] + rq_[1] + rq_[2] + rq_[3];
  const float mu  = s * (1.0f / HID);
  const float var = sq * (1.0f / HID) - mu * mu;
  const float rstd = rsqrtf(var + 1e-5f);
  const float* gp = gam + (size_t)e * HID + tid * 8;
  const float* bp = bet + (size_t)e * HID + tid * 8;
  short8 o;
#pragma unroll
  for (int q = 0; q < 8; ++q) {
    float t = (v[q] - mu) * rstd * gp[q] + bp[q];
    o[q] = (short)f2h(gelu_exact(t));
  }
  *(short8*)(dst + (size_t)(g - c0) * HID + tid * 8) = o;
}

// ---------------- deterministic 2-row combine (fp16 Y -> f32 out) ------------
__global__ __launch_bounds__(256) void combine_kernel(
    const unsigned short* __restrict__ Y, const int* __restrict__ pair,
    float* __restrict__ out)
{
  const int n = blockIdx.x;
  const int j = threadIdx.x * 4;
  const int r1 = pair[2 * n], r2 = pair[2 * n + 1];
  u16x4 a = *(const u16x4*)(Y + (size_t)r1 * OUTD + j);
  u16x4 b = *(const u16x4*)(Y + (size_t)r2 * OUTD + j);
  f32x4 o;
#pragma unroll
  for (int qd = 0; qd < 4; ++qd) o[qd] = h2f(a[qd]) + h2f(b[qd]);
  *(f32x4*)(out + (size_t)n * OUTD + j) = o;
}

// fallback diagnostic: encode ws_size (MB) into out[0]
__global__ void probe_kernel(float* out, float v) {
  if (threadIdx.x == 0 && blockIdx.x == 0) out[0] = v;
}

extern "C" void kernel_launch(void* const* d_in, const int* in_sizes, int n_in,
                              void* d_out, int out_size, void* d_ws, size_t ws_size,
                              hipStream_t stream) {
  (void)in_sizes; (void)n_in;
  const float* x   = (const float*)d_in[0];
  const float* Wg1 = (const float*)d_in[1];
  const float* Wg2 = (const float*)d_in[2];
  const float* W1  = (const float*)d_in[3];
  const float* b1  = (const float*)d_in[4];
  const float* g1  = (const float*)d_in[5];
  const float* be1 = (const float*)d_in[6];
  const float* W2  = (const float*)d_in[7];
  const float* b2  = (const float*)d_in[8];
  const float* g2  = (const float*)d_in[9];
  const float* be2 = (const float*)d_in[10];
  const float* W3  = (const float*)d_in[11];
  const float* b3  = (const float*)d_in[12];
  float* out = (float*)d_out;

  uint8_t* w = (uint8_t*)d_ws;
  auto alloc = [&](size_t bytes) {
    uint8_t* p = w;
    w += (bytes + 255) & ~(size_t)255;
    return p;
  };
  unsigned short* xh   = (unsigned short*)alloc((size_t)N_TOK * DIM * 2);
  unsigned short* Wt1  = (unsigned short*)alloc((size_t)NEXP * DIM * HID * 2);
  unsigned short* Wt2  = (unsigned short*)alloc((size_t)NEXP * HID * HID * 2);
  unsigned short* Wt3  = (unsigned short*)alloc((size_t)NEXP * HID * OUTD * 2);
  int*   rows  = (int*)alloc((size_t)PADTOT * 4);
  float* roww  = (float*)alloc((size_t)PADTOT * 4);
  int*   tok_e = (int*)alloc((size_t)2 * N_TOK * 4);
  float* tok_w = (float*)alloc((size_t)2 * N_TOK * 4);
  int*   pair  = (int*)alloc((size_t)2 * N_TOK * 4);
  int*   cnt   = (int*)alloc(256);
  int*   off   = (int*)alloc(256);
  int*   cur   = (int*)alloc(256);
  size_t fixed_used = (size_t)(w - (uint8_t*)d_ws);

  // adaptive chunk rows: act1h (fp16) + act2 (fp16) = 8192 B/row, 256-row granules
  long long availLL = (long long)ws_size - (long long)fixed_used - 4096;
  int R = 0;
  if (availLL > 0) {
    long long r = availLL / (HID * 2 + HID * 2);
    if (r > PADTOT) r = PADTOT;
    R = (int)(r & ~255LL);
  }
  if (R < 256) {   // diagnostic fallback: out[0] = ws_size in MB
    hipMemsetAsync(d_out, 0, (size_t)out_size * sizeof(float), stream);
    probe_kernel<<<1, 64, 0, stream>>>(out, (float)(ws_size >> 20));
    return;
  }
  unsigned short* act1h = (unsigned short*)alloc((size_t)R * HID * 2);
  unsigned short* act2  = (unsigned short*)alloc((size_t)R * HID * 2);
  const bool single = (R >= PADTOT);   // Y (fp16 [PADTOT][1024]) aliases act1h
  unsigned short* Yh = act1h;

  hipMemsetAsync(cnt, 0, NEXP * sizeof(int), stream);
  hipMemsetAsync(rows, 0, (size_t)PADTOT * 4, stream);   // dummy rows -> token 0
  hipMemsetAsync(roww, 0, (size_t)PADTOT * 4, stream);   // dummy weight -> 0.0
  if (!single)
    hipMemsetAsync(d_out, 0, (size_t)out_size * sizeof(float), stream);  // atomic target

  gate_kernel<<<N_TOK / 8, 256, 0, stream>>>(x, Wg1, Wg2, tok_e, tok_w);
  hist_kernel<<<2 * N_TOK / 512, 256, 0, stream>>>(tok_e, cnt);
  offsets_kernel<<<1, 64, 0, stream>>>(cnt, off, cur);
  scatter_kernel<<<N_TOK / 256, 256, 0, stream>>>(tok_e, tok_w, cur, rows, roww, pair);

  convert_x_kernel<<<(N_TOK * DIM / 8) / 256, 256, 0, stream>>>(x, xh);
  wconv_kernel<<<dim3(HID / 32, DIM / 32, NEXP), 256, 0, stream>>>(W1, Wt1, DIM, HID);
  wconv_kernel<<<dim3(HID / 32, HID / 32, NEXP), 256, 0, stream>>>(W2, Wt2, HID, HID);
  wconv_kernel<<<dim3(OUTD / 32, HID / 32, NEXP), 256, 0, stream>>>(W3, Wt3, HID, OUTD);

  for (int c0 = 0; c0 < PADTOT; c0 += R) {
    int Rc = PADTOT - c0; if (Rc > R) Rc = R;
    const int yt = Rc / 256;
    gemm256_kernel<0><<<8 * yt, 512, 0, stream>>>(xh, Wt1, act1h, nullptr, b1,
                                                  rows, roww, off, DIM, HID, DIM, c0, 3);
    ln_gelu_kernel<<<Rc, 256, 0, stream>>>(act1h, act2, g1, be1, off, c0);
    gemm256_kernel<1><<<8 * yt, 512, 0, stream>>>(act2, Wt2, act1h, nullptr, b2,
                                                  rows, roww, off, HID, HID, HID, c0, 3);
    ln_gelu_kernel<<<Rc, 256, 0, stream>>>(act1h, act2, g2, be2, off, c0);
    if (single)
      gemm256_kernel<3><<<4 * yt, 512, 0, stream>>>(act2, Wt3, Yh, nullptr, b3,
                                                    rows, roww, off, HID, OUTD, HID, c0, 2);
    else
      gemm256_kernel<2><<<4 * yt, 512, 0, stream>>>(act2, Wt3, nullptr, out, b3,
                                                    rows, roww, off, HID, OUTD, HID, c0, 2);
  }
  if (single)
    combine_kernel<<<N_TOK, 256, 0, stream>>>(Yh, pair, out);
}

// Round 10
// 1420.989 us; speedup vs baseline: 1.9457x; 1.0158x over previous
//
#include <hip/hip_runtime.h>
#include <math.h>
#include <stdint.h>

#define N_TOK 16384
#define DIM   1024
#define NEXP  8
#define HID   2048
#define OUTD  1024
#define PADTOT 34816   // 2*N_TOK + 8*256 : padded compacted-row upper bound (136 tiles of 256)

typedef __attribute__((ext_vector_type(8))) short short8;
typedef __attribute__((ext_vector_type(8))) _Float16 f16x8;
typedef __attribute__((ext_vector_type(4))) float f32x4;
typedef __attribute__((ext_vector_type(4))) unsigned short u16x4;

__device__ __forceinline__ unsigned short f2h(float f) {
  return __builtin_bit_cast(unsigned short, (_Float16)f);   // RNE
}
__device__ __forceinline__ float h2f(unsigned short h) {
  return (float)__builtin_bit_cast(_Float16, h);
}
__device__ __forceinline__ float gelu_exact(float a) {
  return 0.5f * a * (1.0f + erff(a * 0.70710678118654752f));
}

// ---------------- gate: fp64 math, high-TLP, NO global atomics ----------------
__global__ __launch_bounds__(256) void gate_kernel(
    const float* __restrict__ x, const float* __restrict__ Wg1,
    const float* __restrict__ Wg2,
    int* __restrict__ tok_e, float* __restrict__ tok_w)
{
  const int tid = threadIdx.x;
  const int lane = tid & 63, wid = tid >> 6;
  const f32x4* __restrict__ Wg1v = (const f32x4*)Wg1;   // [1024][4xf32x4]
  f32x4 wreg[4][4];
#pragma unroll
  for (int i = 0; i < 4; ++i)
#pragma unroll
    for (int c = 0; c < 4; ++c)
      wreg[i][c] = Wg1v[(size_t)(tid + 256 * i) * 4 + c];

  __shared__ double red[4 * 16];

  for (int tk = 0; tk < 8; ++tk) {
    const int n = blockIdx.x * 8 + tk;
    double xv[4];
#pragma unroll
    for (int i = 0; i < 4; ++i)
      xv[i] = (double)x[(size_t)n * DIM + tid + 256 * i];
    double acc[16];
#pragma unroll
    for (int j = 0; j < 16; ++j) acc[j] = 0.0;
#pragma unroll
    for (int i = 0; i < 4; ++i)
#pragma unroll
      for (int c = 0; c < 4; ++c)
#pragma unroll
        for (int q = 0; q < 4; ++q)
          acc[c * 4 + q] += xv[i] * (double)wreg[i][c][q];
#pragma unroll
    for (int j = 0; j < 16; ++j)
#pragma unroll
      for (int s = 32; s > 0; s >>= 1) acc[j] += __shfl_xor(acc[j], s);
    if (lane == 0) {
#pragma unroll
      for (int j = 0; j < 16; ++j) red[wid * 16 + j] = acc[j];
    }
    __syncthreads();
    if (wid == 0) {
      double t = 0.0;
      if (lane < 16) {
        t = red[lane] + red[16 + lane] + red[32 + lane] + red[48 + lane];
        t = tanh(t);
      }
      const int e = lane & 7;
      double ge = 0.0;
#pragma unroll
      for (int j = 0; j < 16; ++j) {
        double tj = __shfl(t, j);
        ge += tj * (double)Wg2[j * 8 + e];
      }
      double m = ge;
#pragma unroll
      for (int s = 1; s < 8; s <<= 1) m = fmax(m, __shfl_xor(m, s));
      double p = exp(ge - m);
      double ssum = p;
#pragma unroll
      for (int s = 1; s < 8; s <<= 1) ssum += __shfl_xor(ssum, s);
      double wsm = p / ssum;
      unsigned long long key =
          (((unsigned long long)__double_as_longlong(wsm)) & ~7ULL) |
          (unsigned long long)(7 - e);
      unsigned long long k1 = key;
#pragma unroll
      for (int s = 1; s < 8; s <<= 1) { unsigned long long o = __shfl_xor(k1, s); k1 = (o > k1) ? o : k1; }
      int e1 = 7 - (int)(k1 & 7ULL);
      unsigned long long k2 = (e == e1) ? 0ULL : key;
#pragma unroll
      for (int s = 1; s < 8; s <<= 1) { unsigned long long o = __shfl_xor(k2, s); k2 = (o > k2) ? o : k2; }
      int e2 = 7 - (int)(k2 & 7ULL);
      double w1v = __longlong_as_double((long long)(k1 & ~7ULL));
      double w2v = __longlong_as_double((long long)(k2 & ~7ULL));
      double inv = 1.0 / (w1v + w2v + 1e-12);
      if (lane == 0) {
        tok_e[2 * n] = e1; tok_e[2 * n + 1] = e2;
        tok_w[2 * n] = (float)(w1v * inv); tok_w[2 * n + 1] = (float)(w2v * inv);
      }
    }
    __syncthreads();
  }
}

// ---------------- hist: LDS histogram, 8 global atomics per block ------------
__global__ __launch_bounds__(256) void hist_kernel(
    const int* __restrict__ tok_e, int* __restrict__ cnt)
{
  __shared__ int h[NEXP];
  const int tid = threadIdx.x;
  if (tid < NEXP) h[tid] = 0;
  __syncthreads();
  const int base = blockIdx.x * 512;
  atomicAdd(&h[tok_e[base + tid]], 1);
  atomicAdd(&h[tok_e[base + 256 + tid]], 1);
  __syncthreads();
  if (tid < NEXP) atomicAdd(&cnt[tid], h[tid]);
}

// offsets padded to multiples of 256 so every 256-row tile is single-expert
__global__ void offsets_kernel(const int* __restrict__ cnt, int* __restrict__ off,
                               int* __restrict__ cur) {
  if (threadIdx.x == 0) {
    int a = 0;
    for (int e = 0; e < NEXP; ++e) {
      off[e] = a; cur[e] = a;
      a += (cnt[e] + 255) & ~255;
    }
    off[NEXP] = a;
  }
}

// ---------------- scatter: per-block LDS rank + one base-claim per expert ----
__global__ __launch_bounds__(256) void scatter_kernel(
    const int* __restrict__ tok_e, const float* __restrict__ tok_w,
    int* __restrict__ cur, int* __restrict__ rows, float* __restrict__ roww,
    int* __restrict__ pair)
{
  __shared__ int lcnt[NEXP];
  __shared__ int lbase[NEXP];
  const int tid = threadIdx.x;
  if (tid < NEXP) lcnt[tid] = 0;
  __syncthreads();
  const int n = blockIdx.x * 256 + tid;
  const int e0 = tok_e[2 * n], e1 = tok_e[2 * n + 1];
  const int r0 = atomicAdd(&lcnt[e0], 1);
  const int r1 = atomicAdd(&lcnt[e1], 1);
  __syncthreads();
  if (tid < NEXP) lbase[tid] = atomicAdd(&cur[tid], lcnt[tid]);
  __syncthreads();
  const int p0 = lbase[e0] + r0;
  const int p1 = lbase[e1] + r1;
  rows[p0] = n; roww[p0] = tok_w[2 * n];     pair[2 * n]     = p0;
  rows[p1] = n; roww[p1] = tok_w[2 * n + 1]; pair[2 * n + 1] = p1;
}

// ---------------- fp32 -> fp16 converts ----------------
__global__ __launch_bounds__(256) void convert_x_kernel(
    const float* __restrict__ x, unsigned short* __restrict__ xh)
{
  size_t i = ((size_t)blockIdx.x * 256 + threadIdx.x) * 8;
  f32x4 a = *(const f32x4*)(x + i);
  f32x4 b = *(const f32x4*)(x + i + 4);
  short8 o;
#pragma unroll
  for (int q = 0; q < 4; ++q) { o[q] = (short)f2h(a[q]); o[q + 4] = (short)f2h(b[q]); }
  *(short8*)(xh + i) = o;
}

// transpose+convert: W[e][K][N] fp32 -> Wt[e][N][K] fp16
__global__ __launch_bounds__(256) void wconv_kernel(
    const float* __restrict__ W, unsigned short* __restrict__ Wt,
    const int K, const int N)
{
  __shared__ float t[32][33];
  const int e = blockIdx.z;
  const float* We = W + (size_t)e * K * N;
  unsigned short* Wte = Wt + (size_t)e * K * N;
  const int n0 = blockIdx.x * 32, k0 = blockIdx.y * 32;
  const int tid = threadIdx.x;
  const int r = tid >> 3, c4 = (tid & 7) * 4;
  f32x4 v = *(const f32x4*)(We + (size_t)(k0 + r) * N + n0 + c4);
  t[r][c4 + 0] = v[0]; t[r][c4 + 1] = v[1]; t[r][c4 + 2] = v[2]; t[r][c4 + 3] = v[3];
  __syncthreads();
  u16x4 o;
#pragma unroll
  for (int q = 0; q < 4; ++q) o[q] = f2h(t[c4 + q][r]);
  *(u16x4*)(Wte + (size_t)(n0 + r) * K + k0 + c4) = o;
}

// ============ 256x256 8-wave routed GEMM, 2-barrier/K-tile, fragment-reuse ============
// Per tile: STAGEA(t+1); read af0+bf; 32 MFMA; lgkm0+bar; STAGEB(t+2); read af1;
// 32 MFMA; vmcnt(4)+lgkm0+bar.  No artificial read/MFMA barriers.
// MODE 0: A = gathered xh rows; MODE 1: A = act2; MODE 2: atomic fallback; MODE 3: Y out.

#define STAGEA(SB_, T_) do {                                                  \
  _Pragma("unroll") for (int qm_ = 0; qm_ < 2; ++qm_)                         \
  _Pragma("unroll") for (int i_ = 0; i_ < 2; ++i_)                            \
    __builtin_amdgcn_global_load_lds(                                         \
      (const __attribute__((address_space(1))) void*)(Abase + aoff[qm_][i_] + (size_t)(T_)*64 + kc8), \
      (__attribute__((address_space(3))) void*)(lds + (SB_)*16384 + qm_*4096 + i_*8192 + tid*8), \
      16, 0, 0);                                                              \
} while (0)

// dest = B + qn*2048 + (i*2 + (tid>>8))*4096 + (tid&255)*8   [round-8 verified layout]
#define STAGEB(SB_, T_) do {                                                  \
  _Pragma("unroll") for (int qn_ = 0; qn_ < 2; ++qn_)                         \
  _Pragma("unroll") for (int i_ = 0; i_ < 2; ++i_)                            \
    __builtin_amdgcn_global_load_lds(                                         \
      (const __attribute__((address_space(1))) void*)(Bbase + boff[qn_][i_] + (size_t)(T_)*64 + kc8), \
      (__attribute__((address_space(3))) void*)(lds + 32768 + (SB_)*16384 + qn_*2048 + (i_*2 + (tid >> 8))*4096 + (tid & 255)*8), \
      16, 0, 0);                                                              \
} while (0)

#define LOAD_AF(QM_) do {                                                     \
    _Pragma("unroll") for (int mi = 0; mi < 4; ++mi)                          \
    _Pragma("unroll") for (int kk = 0; kk < 2; ++kk) {                        \
      const int row_ = wm*128 + (QM_)*64 + mi*16 + l15;                       \
      const int ch_ = ((kk*4 + lh) ^ (row_ & 7));                             \
      af[mi][kk] = *(const short8*)(ldsAb + row_*64 + ch_*8);                 \
    }                                                                         \
} while (0)

#define LOAD_BF() do {                                                        \
    _Pragma("unroll") for (int qn = 0; qn < 2; ++qn)                          \
    _Pragma("unroll") for (int ni = 0; ni < 2; ++ni)                          \
    _Pragma("unroll") for (int kk = 0; kk < 2; ++kk) {                        \
      const int row_ = wn*64 + qn*32 + ni*16 + l15;                           \
      const int ch_ = ((kk*4 + lh) ^ (row_ & 7));                             \
      bf[qn][ni][kk] = *(const short8*)(ldsBb + row_*64 + ch_*8);             \
    }                                                                         \
} while (0)

// 32 MFMA: half QM_ x all 4 column-fragments x K=64
#define MFMA_HALF(QM_) do {                                                   \
    __builtin_amdgcn_s_setprio(1);                                            \
    _Pragma("unroll") for (int kk = 0; kk < 2; ++kk)                          \
    _Pragma("unroll") for (int mi = 0; mi < 4; ++mi)                          \
    _Pragma("unroll") for (int qn = 0; qn < 2; ++qn)                          \
    _Pragma("unroll") for (int ni = 0; ni < 2; ++ni)                          \
      acc[(QM_)*4 + mi][qn*2 + ni] = __builtin_amdgcn_mfma_f32_16x16x32_f16(  \
          __builtin_bit_cast(f16x8, bf[qn][ni][kk]),                          \
          __builtin_bit_cast(f16x8, af[mi][kk]),                              \
          acc[(QM_)*4 + mi][qn*2 + ni], 0, 0, 0);                             \
    __builtin_amdgcn_s_setprio(0);                                            \
} while (0)

// mid-tile sync: drain this wave's LDS reads (so B[b] truly read) then barrier
#define SYNC_LGKM_BAR() do {                                                  \
  asm volatile("s_waitcnt lgkmcnt(0)" ::: "memory");                          \
  asm volatile("s_barrier" ::: "memory");                                     \
} while (0)
// tile-end sync: counted vmcnt (staged data ready) + lgkm drain + barrier
#define PH_END(N_) do {                                                       \
  asm volatile("s_waitcnt vmcnt(" #N_ ") lgkmcnt(0)" ::: "memory");           \
  asm volatile("s_barrier" ::: "memory");                                     \
} while (0)

template<int MODE>
__global__ __launch_bounds__(512, 1) void gemm256_kernel(
    const unsigned short* __restrict__ Abase,
    const unsigned short* __restrict__ Bbase,
    unsigned short* __restrict__ Oh,
    float* __restrict__ Of,
    const float* __restrict__ bias,
    const int* __restrict__ rows,
    const float* __restrict__ roww,
    const int* __restrict__ off,
    const int K, const int N, const int Astride, const int c0, const int lgGX)
{
  // XCD-chunked bijective block remap (m204)
  const unsigned orig = blockIdx.x, nwg = gridDim.x;
  const unsigned q8 = nwg >> 3, r8 = nwg & 7;
  const unsigned xcd = orig & 7, pos = orig >> 3;
  const unsigned wrk = (xcd < r8 ? xcd * (q8 + 1) : r8 * (q8 + 1) + (xcd - r8) * q8) + pos;
  const int tn = (int)(wrk & ((1u << lgGX) - 1u));
  const int rowbase = c0 + (int)(wrk >> lgGX) * 256;

  const int off8 = off[NEXP];
  if (rowbase >= off8) return;
  int e = 0;
  while (e < NEXP - 1 && rowbase >= off[e + 1]) ++e;

  // LDS: A[2 buf][256][64] fp16 @0, B[2 buf][256][64] fp16 @32768 shorts = 128 KiB
  __shared__ __align__(16) unsigned short lds[65536];

  const int tid = threadIdx.x, lane = tid & 63, wid = tid >> 6;
  const int wm = wid >> 2, wn = wid & 3;       // 2 x 4 waves, each owns 128x64
  const int l15 = lane & 15, lh = lane >> 4;
  const int kc8 = ((tid & 7) ^ ((tid >> 3) & 7)) * 8;   // pre-swizzled source chunk

  f32x4 acc[8][4] = {};

  // per-thread staging offsets (element units)
  size_t aoff[2][2];
#pragma unroll
  for (int qm = 0; qm < 2; ++qm)
#pragma unroll
    for (int i = 0; i < 2; ++i) {
      int grow = rowbase + i * 128 + qm * 64 + (tid >> 3);
      size_t arow = (MODE == 0) ? (size_t)rows[grow] : (size_t)(grow - c0);
      aoff[qm][i] = arow * (size_t)Astride;
    }
  size_t boff[2][2];
#pragma unroll
  for (int qn = 0; qn < 2; ++qn)
#pragma unroll
    for (int i = 0; i < 2; ++i) {
      int rl = i * 64 + (tid >> 3);
      int brow = (rl >> 5) * 64 + qn * 32 + (rl & 31);
      boff[qn][i] = ((size_t)e * N + (size_t)(tn * 256 + brow)) * (size_t)K;
    }

  const int nt = K >> 6;
  // prologue: SA(0), SB(0) into buf0; SB(1) into buf1.  vmcnt(4): t0 A+B done.
  STAGEA(0, 0); STAGEB(0, 0); STAGEB(1, 1);
  PH_END(4);

  for (int t = 0; t < nt; ++t) {
    const int b = t & 1;
    const unsigned short* ldsAb = lds + b * 16384;
    const unsigned short* ldsBb = lds + 32768 + b * 16384;
    short8 af[4][2], bf[2][2][2];
    // stage next A (A[b^1] free since t-1's tile-end barrier); read af0 + bf; top half
    if (t + 1 < nt) STAGEA(b ^ 1, t + 1);
    LOAD_AF(0); LOAD_BF();
    MFMA_HALF(0);
    SYNC_LGKM_BAR();                 // all waves' B[b]/A[b]-top reads complete
    // stage t+2's B into dying B[b]; read af1; bottom half
    if (t + 2 < nt) STAGEB(b, t + 2);
    LOAD_AF(1);
    MFMA_HALF(1);
    if (t + 2 < nt) PH_END(4); else PH_END(0);   // SA(t+1)+SB(t+1) complete
  }

  if (MODE == 2) {
    // fallback: scattered f32 atomics into d_out
#pragma unroll
    for (int mi = 0; mi < 8; ++mi) {
      int g = rowbase + wm * 128 + mi * 16 + l15;
      int token = rows[g];
      float wgt = roww[g];
#pragma unroll
      for (int ni = 0; ni < 4; ++ni) {
        int n = tn * 256 + wn * 64 + ni * 16 + lh * 4;
        f32x4 v = acc[mi][ni];
        f32x4 bv = *(const f32x4*)(bias + (size_t)e * N + n);
#pragma unroll
        for (int qd = 0; qd < 4; ++qd)
          atomicAdd(&Of[(size_t)token * N + n + qd], wgt * (v[qd] + bv[qd]));
      }
    }
    return;
  }

  // epilogue: acc -> swizzled fp16 tile in LDS (reuse staging LDS) -> coalesced stores
  __syncthreads();
#pragma unroll
  for (int mi = 0; mi < 8; ++mi) {
    const int row = wm * 128 + mi * 16 + l15;
    float wgt = 1.0f;
    if (MODE == 3) wgt = roww[rowbase + row];
#pragma unroll
    for (int ni = 0; ni < 4; ++ni) {
      const int col = wn * 64 + ni * 16 + lh * 4;
      f32x4 v = acc[mi][ni];
      f32x4 bv = *(const f32x4*)(bias + (size_t)e * N + tn * 256 + col);
      u16x4 h;
#pragma unroll
      for (int qd = 0; qd < 4; ++qd) {
        float vv = v[qd] + bv[qd];
        if (MODE == 3) vv *= wgt;
        h[qd] = f2h(vv);
      }
      const int ch = (col >> 3) ^ (row & 7);
      *(u16x4*)(lds + row * 256 + ch * 8 + (col & 7)) = h;
    }
  }
  __syncthreads();
#pragma unroll
  for (int it = 0; it < 16; ++it) {
    const int flat = it * 512 + tid;
    const int row = flat >> 5;              // 0..255
    const int ch = flat & 31;               // 32 x 16B = full 512B row
    const int chs = ch ^ (row & 7);
    short8 v = *(const short8*)(lds + row * 256 + chs * 8);
    const int g = rowbase + row;
    unsigned short* dst = (MODE == 3) ? (Oh + (size_t)g * N)
                                      : (Oh + (size_t)(g - c0) * N);
    *(short8*)(dst + tn * 256 + ch * 8) = v;
  }
}

// ---------------- LayerNorm + exact GELU: fp16 in, fp16 out (f32 stats) ------
__global__ __launch_bounds__(256) void ln_gelu_kernel(
    const unsigned short* __restrict__ src, unsigned short* __restrict__ dst,
    const float* __restrict__ gam, const float* __restrict__ bet,
    const int* __restrict__ off, const int c0)
{
  const int g = c0 + blockIdx.x;
  if (g >= off[NEXP]) return;
  int e = 0;
#pragma unroll
  for (int q = 1; q < NEXP; ++q) if (g >= off[q]) e = q;
  const int tid = threadIdx.x;
  const unsigned short* s0 = src + (size_t)(g - c0) * HID;
  short8 hv = *(const short8*)(s0 + tid * 8);
  float v[8];
  float s = 0.f, sq = 0.f;
#pragma unroll
  for (int q = 0; q < 8; ++q) {
    v[q] = h2f((unsigned short)hv[q]);
    s += v[q]; sq += v[q] * v[q];
  }
#pragma unroll
  for (int sh = 32; sh > 0; sh >>= 1) { s += __shfl_xor(s, sh); sq += __shfl_xor(sq, sh); }
  __shared__ float rs_[4], rq_[4];
  const int lane = tid & 63, wid = tid >> 6;
  if (lane == 0) { rs_[wid] = s; rq_[wid] = sq; }
  __syncthreads();
  s  = rs_[0] + rs_[1] + rs_[2] + rs_[3];
  sq = rq_[0] + rq_[1] + rq_[2] + rq_[3];
  const float mu  = s * (1.0f / HID);
  const float var = sq * (1.0f / HID) - mu * mu;
  const float rstd = rsqrtf(var + 1e-5f);
  const float* gp = gam + (size_t)e * HID + tid * 8;
  const float* bp = bet + (size_t)e * HID + tid * 8;
  short8 o;
#pragma unroll
  for (int q = 0; q < 8; ++q) {
    float t = (v[q] - mu) * rstd * gp[q] + bp[q];
    o[q] = (short)f2h(gelu_exact(t));
  }
  *(short8*)(dst + (size_t)(g - c0) * HID + tid * 8) = o;
}

// ---------------- deterministic 2-row combine (fp16 Y -> f32 out) ------------
__global__ __launch_bounds__(256) void combine_kernel(
    const unsigned short* __restrict__ Y, const int* __restrict__ pair,
    float* __restrict__ out)
{
  const int n = blockIdx.x;
  const int j = threadIdx.x * 4;
  const int r1 = pair[2 * n], r2 = pair[2 * n + 1];
  u16x4 a = *(const u16x4*)(Y + (size_t)r1 * OUTD + j);
  u16x4 b = *(const u16x4*)(Y + (size_t)r2 * OUTD + j);
  f32x4 o;
#pragma unroll
  for (int qd = 0; qd < 4; ++qd) o[qd] = h2f(a[qd]) + h2f(b[qd]);
  *(f32x4*)(out + (size_t)n * OUTD + j) = o;
}

// fallback diagnostic: encode ws_size (MB) into out[0]
__global__ void probe_kernel(float* out, float v) {
  if (threadIdx.x == 0 && blockIdx.x == 0) out[0] = v;
}

extern "C" void kernel_launch(void* const* d_in, const int* in_sizes, int n_in,
                              void* d_out, int out_size, void* d_ws, size_t ws_size,
                              hipStream_t stream) {
  (void)in_sizes; (void)n_in;
  const float* x   = (const float*)d_in[0];
  const float* Wg1 = (const float*)d_in[1];
  const float* Wg2 = (const float*)d_in[2];
  const float* W1  = (const float*)d_in[3];
  const float* b1  = (const float*)d_in[4];
  const float* g1  = (const float*)d_in[5];
  const float* be1 = (const float*)d_in[6];
  const float* W2  = (const float*)d_in[7];
  const float* b2  = (const float*)d_in[8];
  const float* g2  = (const float*)d_in[9];
  const float* be2 = (const float*)d_in[10];
  const float* W3  = (const float*)d_in[11];
  const float* b3  = (const float*)d_in[12];
  float* out = (float*)d_out;

  uint8_t* w = (uint8_t*)d_ws;
  auto alloc = [&](size_t bytes) {
    uint8_t* p = w;
    w += (bytes + 255) & ~(size_t)255;
    return p;
  };
  unsigned short* xh   = (unsigned short*)alloc((size_t)N_TOK * DIM * 2);
  unsigned short* Wt1  = (unsigned short*)alloc((size_t)NEXP * DIM * HID * 2);
  unsigned short* Wt2  = (unsigned short*)alloc((size_t)NEXP * HID * HID * 2);
  unsigned short* Wt3  = (unsigned short*)alloc((size_t)NEXP * HID * OUTD * 2);
  int*   rows  = (int*)alloc((size_t)PADTOT * 4);
  float* roww  = (float*)alloc((size_t)PADTOT * 4);
  int*   tok_e = (int*)alloc((size_t)2 * N_TOK * 4);
  float* tok_w = (float*)alloc((size_t)2 * N_TOK * 4);
  int*   pair  = (int*)alloc((size_t)2 * N_TOK * 4);
  int*   cnt   = (int*)alloc(256);
  int*   off   = (int*)alloc(256);
  int*   cur   = (int*)alloc(256);
  size_t fixed_used = (size_t)(w - (uint8_t*)d_ws);

  // adaptive chunk rows: act1h (fp16) + act2 (fp16) = 8192 B/row, 256-row granules
  long long availLL = (long long)ws_size - (long long)fixed_used - 4096;
  int R = 0;
  if (availLL > 0) {
    long long r = availLL / (HID * 2 + HID * 2);
    if (r > PADTOT) r = PADTOT;
    R = (int)(r & ~255LL);
  }
  if (R < 256) {   // diagnostic fallback: out[0] = ws_size in MB
    hipMemsetAsync(d_out, 0, (size_t)out_size * sizeof(float), stream);
    probe_kernel<<<1, 64, 0, stream>>>(out, (float)(ws_size >> 20));
    return;
  }
  unsigned short* act1h = (unsigned short*)alloc((size_t)R * HID * 2);
  unsigned short* act2  = (unsigned short*)alloc((size_t)R * HID * 2);
  const bool single = (R >= PADTOT);   // Y (fp16 [PADTOT][1024]) aliases act1h
  unsigned short* Yh = act1h;

  hipMemsetAsync(cnt, 0, NEXP * sizeof(int), stream);
  hipMemsetAsync(rows, 0, (size_t)PADTOT * 4, stream);   // dummy rows -> token 0
  hipMemsetAsync(roww, 0, (size_t)PADTOT * 4, stream);   // dummy weight -> 0.0
  if (!single)
    hipMemsetAsync(d_out, 0, (size_t)out_size * sizeof(float), stream);  // atomic target

  gate_kernel<<<N_TOK / 8, 256, 0, stream>>>(x, Wg1, Wg2, tok_e, tok_w);
  hist_kernel<<<2 * N_TOK / 512, 256, 0, stream>>>(tok_e, cnt);
  offsets_kernel<<<1, 64, 0, stream>>>(cnt, off, cur);
  scatter_kernel<<<N_TOK / 256, 256, 0, stream>>>(tok_e, tok_w, cur, rows, roww, pair);

  convert_x_kernel<<<(N_TOK * DIM / 8) / 256, 256, 0, stream>>>(x, xh);
  wconv_kernel<<<dim3(HID / 32, DIM / 32, NEXP), 256, 0, stream>>>(W1, Wt1, DIM, HID);
  wconv_kernel<<<dim3(HID / 32, HID / 32, NEXP), 256, 0, stream>>>(W2, Wt2, HID, HID);
  wconv_kernel<<<dim3(OUTD / 32, HID / 32, NEXP), 256, 0, stream>>>(W3, Wt3, HID, OUTD);

  for (int c0 = 0; c0 < PADTOT; c0 += R) {
    int Rc = PADTOT - c0; if (Rc > R) Rc = R;
    const int yt = Rc / 256;
    gemm256_kernel<0><<<8 * yt, 512, 0, stream>>>(xh, Wt1, act1h, nullptr, b1,
                                                  rows, roww, off, DIM, HID, DIM, c0, 3);
    ln_gelu_kernel<<<Rc, 256, 0, stream>>>(act1h, act2, g1, be1, off, c0);
    gemm256_kernel<1><<<8 * yt, 512, 0, stream>>>(act2, Wt2, act1h, nullptr, b2,
                                                  rows, roww, off, HID, HID, HID, c0, 3);
    ln_gelu_kernel<<<Rc, 256, 0, stream>>>(act1h, act2, g2, be2, off, c0);
    if (single)
      gemm256_kernel<3><<<4 * yt, 512, 0, stream>>>(act2, Wt3, Yh, nullptr, b3,
                                                    rows, roww, off, HID, OUTD, HID, c0, 2);
    else
      gemm256_kernel<2><<<4 * yt, 512, 0, stream>>>(act2, Wt3, nullptr, out, b3,
                                                    rows, roww, off, HID, OUTD, HID, c0, 2);
  }
  if (single)
    combine_kernel<<<N_TOK, 256, 0, stream>>>(Yh, pair, out);
}